// Round 3
// baseline (34171.808 us; speedup 1.0000x reference)
//
#include <hip/hip_runtime.h>

// LSTMForecast: B=256, T=512, IN=32, H=256, OUT=1, fp32.
// Round 3: balanced C=86 blocks x R=3 rows/block (Round-2 design, macro bug fixed).
//   - weights repacked [k][j][4 gates] float4 -> one dwordx4 per k per thread
//   - 768 threads = 3 row-groups x 256 j; h in LDS, float4 broadcast reads
//   - L2 floor ~4.2 ms = VALU floor at C=86

#define TT 512
#define HH 256
#define BB 256
#define INDIM 32
#define K0 288   // 32 (x) + 256 (h0)
#define K1 512   // 256 (h0) + 256 (h1)

// ws layout (floats)
constexpr int WP0_OFF = 0;                    // [288][256][4] = 294912 floats
constexpr int WP1_OFF = 294912;               // [512][256][4] = 524288 floats
constexpr int BC0_OFF = WP1_OFF + 524288;     // [256][4]
constexpr int BC1_OFF = BC0_OFF + 1024;
constexpr int WS_FLOATS = BC1_OFF + 1024;     // 821248 floats ~ 3.29 MB

__device__ __forceinline__ void fma4(float4& a, const float4& b, float s) {
  a.x = fmaf(b.x, s, a.x);
  a.y = fmaf(b.y, s, a.y);
  a.z = fmaf(b.z, s, a.z);
  a.w = fmaf(b.w, s, a.w);
}

__device__ __forceinline__ float sigmoidf_(float v) { return 1.0f / (1.0f + expf(-v)); }

__global__ void pack_weights(const float* __restrict__ Wih0, const float* __restrict__ Whh0,
                             const float* __restrict__ bih0, const float* __restrict__ bhh0,
                             const float* __restrict__ Wih1, const float* __restrict__ Whh1,
                             const float* __restrict__ bih1, const float* __restrict__ bhh1,
                             float* __restrict__ ws) {
  int idx = blockIdx.x * blockDim.x + threadIdx.x;
  if (idx < 294912) {                 // WP0: [k][j][g]
    int g = idx & 3, f4 = idx >> 2;
    int j = f4 & 255, k = f4 >> 8;    // k in [0,288)
    int n = g * 256 + j;
    ws[WP0_OFF + idx] = (k < INDIM) ? Wih0[n * INDIM + k] : Whh0[n * HH + (k - INDIM)];
    return;
  }
  if (idx < 819200) {                 // WP1: [k][j][g]
    int e = idx - 294912;
    int g = e & 3, f4 = e >> 2;
    int j = f4 & 255, k = f4 >> 8;    // k in [0,512)
    int n = g * 256 + j;
    ws[WP1_OFF + e] = (k < HH) ? Wih1[n * HH + k] : Whh1[n * HH + (k - HH)];
    return;
  }
  if (idx < 820224) {                 // BC0: [j][g]
    int e = idx - 819200;
    int g = e & 3, j = e >> 2;
    ws[BC0_OFF + e] = bih0[g * 256 + j] + bhh0[g * 256 + j];
    return;
  }
  if (idx < WS_FLOATS) {              // BC1
    int e = idx - 820224;
    int g = e & 3, j = e >> 2;
    ws[BC1_OFF + e] = bih1[g * 256 + j] + bhh1[g * 256 + j];
    return;
  }
}

__global__ __launch_bounds__(768, 3) void lstm_forecast(
    const float* __restrict__ x,      // [B][T][IN]
    const float* __restrict__ ws,
    const float* __restrict__ Wfc,    // [1][H]
    const float* __restrict__ bfc,    // [1]
    float* __restrict__ out) {        // [B]
  __shared__ float A0[3][K0];         // [row][ x(0..31) | h0(32..287) ]
  __shared__ float A1[3][K1];         // [row][ h0(0..255) | h1(256..511) ]
  __shared__ float part[12];

  const int tid = threadIdx.x;
  const int r   = tid >> 8;           // 0..2 row within block
  const int j   = tid & 255;          // hidden column

  const float4* WP0 = (const float4*)(ws + WP0_OFF) + j;   // stride 256 float4 per k
  const float4* WP1 = (const float4*)(ws + WP1_OFF) + j;
  const float4  bc0 = ((const float4*)(ws + BC0_OFF))[j];
  const float4  bc1 = ((const float4*)(ws + BC1_OFF))[j];

  // init h regions
  A0[r][32 + j] = 0.0f;
  A1[r][j] = 0.0f;
  A1[r][256 + j] = 0.0f;
  float c0 = 0.0f, c1 = 0.0f, h1v = 0.0f;

  // x staging assignments (threads 0..95: 3 rows x 32 cols)
  int xr = 0, xk = 0;
  float xv = 0.0f;
  if (tid < 96) {
    xr = tid >> 5; xk = tid & 31;
    int bb = blockIdx.x * 3 + xr;
    if (bb < BB) xv = x[((long)bb * TT + 0) * INDIM + xk];
  }

  for (int t = 0; t < TT; ++t) {
    if (tid < 96) A0[xr][xk] = xv;
    __syncthreads();                          // B1: x + prev h1 visible
    if (tid < 96) {                           // prefetch next x (in flight over L0)
      int bb = blockIdx.x * 3 + xr;
      xv = (t + 1 < TT && bb < BB) ? x[((long)bb * TT + (t + 1)) * INDIM + xk] : 0.0f;
    }

    // ---- layer 0: K = 288 over A0[r][*] ----
    float4 acc = bc0;
    {
      const float4* wp = WP0;
      #pragma unroll 4
      for (int kc = 0; kc < K0 / 4; ++kc) {
        float4 w0 = wp[0], w1 = wp[256], w2 = wp[512], w3 = wp[768];
        float4 hv = *(const float4*)&A0[r][kc * 4];
        fma4(acc, w0, hv.x);
        fma4(acc, w1, hv.y);
        fma4(acc, w2, hv.z);
        fma4(acc, w3, hv.w);
        wp += 1024;
      }
    }
    float h0v;
    {
      float iv = sigmoidf_(acc.x);
      float fv = sigmoidf_(acc.y);
      float gv = tanhf(acc.z);
      float ov = sigmoidf_(acc.w);
      c0 = fv * c0 + iv * gv;
      h0v = ov * tanhf(c0);
    }
    __syncthreads();                          // B2: all A0 reads done
    A0[r][32 + j] = h0v;
    A1[r][j] = h0v;
    __syncthreads();                          // B3: new h0 visible

    // ---- layer 1: K = 512 over A1[r][*] ----
    float4 a1 = bc1;
    {
      const float4* wp = WP1;
      #pragma unroll 4
      for (int kc = 0; kc < K1 / 4; ++kc) {
        float4 w0 = wp[0], w1 = wp[256], w2 = wp[512], w3 = wp[768];
        float4 hv = *(const float4*)&A1[r][kc * 4];
        fma4(a1, w0, hv.x);
        fma4(a1, w1, hv.y);
        fma4(a1, w2, hv.z);
        fma4(a1, w3, hv.w);
        wp += 1024;
      }
    }
    {
      float iv = sigmoidf_(a1.x);
      float fv = sigmoidf_(a1.y);
      float gv = tanhf(a1.z);
      float ov = sigmoidf_(a1.w);
      c1 = fv * c1 + iv * gv;
      h1v = ov * tanhf(c1);
    }
    __syncthreads();                          // B4: all A1 reads done
    A1[r][256 + j] = h1v;
    // loop back: x write targets A0[r][0..32) (disjoint from A1), B1 republishes
  }

  // ---- final FC: out[b] = h1 . Wfc + bfc ----
  float v = h1v * Wfc[j];
  #pragma unroll
  for (int off = 32; off > 0; off >>= 1) v += __shfl_down(v, off, 64);
  if ((tid & 63) == 0) part[tid >> 6] = v;
  __syncthreads();
  if (tid < 3) {
    float s = part[tid * 4] + part[tid * 4 + 1] + part[tid * 4 + 2] + part[tid * 4 + 3] + bfc[0];
    int bb = blockIdx.x * 3 + tid;
    if (bb < BB) out[bb] = s;
  }
}

extern "C" void kernel_launch(void* const* d_in, const int* in_sizes, int n_in,
                              void* d_out, int out_size, void* d_ws, size_t ws_size,
                              hipStream_t stream) {
  const float* x    = (const float*)d_in[0];
  const float* Wih0 = (const float*)d_in[1];
  const float* Whh0 = (const float*)d_in[2];
  const float* bih0 = (const float*)d_in[3];
  const float* bhh0 = (const float*)d_in[4];
  const float* Wih1 = (const float*)d_in[5];
  const float* Whh1 = (const float*)d_in[6];
  const float* bih1 = (const float*)d_in[7];
  const float* bhh1 = (const float*)d_in[8];
  const float* Wfc  = (const float*)d_in[9];
  const float* bfc  = (const float*)d_in[10];
  float* out = (float*)d_out;
  float* ws  = (float*)d_ws;

  (void)in_sizes; (void)n_in; (void)out_size; (void)ws_size;

  int pack_threads = 256;
  int pack_blocks = (WS_FLOATS + pack_threads - 1) / pack_threads;
  pack_weights<<<pack_blocks, pack_threads, 0, stream>>>(
      Wih0, Whh0, bih0, bhh0, Wih1, Whh1, bih1, bhh1, ws);

  int nblocks = (BB + 2) / 3;   // 86
  lstm_forecast<<<dim3(nblocks), dim3(768), 0, stream>>>(x, ws, Wfc, bfc, out);
}

// Round 4
// 24436.615 us; speedup vs baseline: 1.3984x; 1.3984x over previous
//
#include <hip/hip_runtime.h>

// LSTMForecast: B=256, T=512, IN=32, H=256, OUT=1, fp32.
// Round 4: weight-stationary split-bf16 MFMA pipeline.
//   - 256 persistent blocks (1/CU): blocks 0-127 = layer0, 128-255 = layer1.
//   - 8 batch-groups x 32 rows; each block owns a 16-j slice of one layer for one group.
//   - Weights: exact bf16 hi+lo split, packed as MFMA B-fragments, resident in VGPRs.
//   - h exchange: bf16(hi|lo) ring buffers (8 slots) in ws; device-scope flag counters.
//   - gates = h @ W^T via mfma_f32_16x16x32_bf16, 4-product split => ~fp32 accuracy.

#define TT 512
#define HB 256

typedef short v8s __attribute__((ext_vector_type(8)));
typedef float v4f __attribute__((ext_vector_type(4)));
typedef unsigned short u4h __attribute__((ext_vector_type(4)));
typedef unsigned short u8h __attribute__((ext_vector_type(8)));

// ws byte offsets
constexpr int OFF_W0    = 0;        // bf16 [16 s][4 n][18 fr][64 lane][8] = 1,179,648 B
constexpr int OFF_W1    = 1179648;  // bf16 [16 s][4 n][32 fr][64 lane][8] = 2,097,152 B
constexpr int OFF_BC0   = 3276800;  // fp32 [1024]
constexpr int OFF_BC1   = 3280896;  // fp32 [1024]
constexpr int OFF_FLG   = 3284992;  // int f0[8], f1[8], r1[8]
constexpr int OFF_RING0 = 3285120;  // bf16 [8 slot][256 b][512] = 2,097,152 B
constexpr int OFF_RING1 = 5382272;  // same
constexpr int SMEM_BYTES = 76544;   // Apan 66048 + gates 8448 + cst 2048

__device__ __forceinline__ float bf2f(unsigned short h){ return __uint_as_float(((unsigned)h)<<16); }
__device__ __forceinline__ unsigned short f2bf(float f){
  unsigned u = __float_as_uint(f);
  u += 0x7FFF + ((u>>16)&1);
  return (unsigned short)(u>>16);
}
__device__ __forceinline__ float sigm(float v){ return 1.0f/(1.0f + expf(-v)); }
__device__ __forceinline__ float tanh_(float v){
  float a = fabsf(v);
  float e = expf(-2.0f*a);
  float r = (1.0f - e)/(1.0f + e);
  return copysignf(r, v);
}
__device__ __forceinline__ int ld_acq(const int* p){
  return __hip_atomic_load(p, __ATOMIC_ACQUIRE, __HIP_MEMORY_SCOPE_AGENT);
}

// ---------------- pack: weights -> split-bf16 MFMA B-fragments; biases; zero rings/flags/out ----
__global__ void pack_all(const float* __restrict__ Wih0, const float* __restrict__ Whh0,
                         const float* __restrict__ bih0, const float* __restrict__ bhh0,
                         const float* __restrict__ Wih1, const float* __restrict__ Whh1,
                         const float* __restrict__ bih1, const float* __restrict__ bhh1,
                         char* __restrict__ ws, float* __restrict__ out){
  int idx = blockIdx.x*256 + threadIdx.x;
  unsigned short* w0 = (unsigned short*)(ws + OFF_W0);
  unsigned short* w1 = (unsigned short*)(ws + OFF_W1);
  if (idx < 294912){  // layer0: [s][n][lk 9][spl 2] frags
    int e = idx&7, lane = (idx>>3)&63, r = idx>>9;
    int lk = r%9; int r2 = r/9; int n = r2&3, s = r2>>2;
    int row = n*256 + s*16 + (lane&15);
    int k = lk*32 + (lane>>4)*8 + e;                 // logical k: 0..31 x, 32..287 h0
    float w = (lk==0) ? Wih0[row*32 + k] : Whh0[row*256 + (k-32)];
    unsigned short hi = f2bf(w);
    unsigned short lo = f2bf(w - bf2f(hi));
    int base = (((s*4+n)*18 + lk*2)*512) + lane*8 + e;
    w0[base] = hi; w0[base + 512] = lo;
    return;
  }
  idx -= 294912;
  if (idx < 524288){  // layer1: [s][n][lk 16][spl 2]
    int e = idx&7, lane = (idx>>3)&63, r = idx>>9;
    int lk = r&15; int r2 = r>>4; int n = r2&3, s = r2>>2;
    int row = n*256 + s*16 + (lane&15);
    int k = lk*32 + (lane>>4)*8 + e;                 // 0..255 h0 (Wih1), 256..511 h1 (Whh1)
    float w = (k<256) ? Wih1[row*256 + k] : Whh1[row*256 + (k-256)];
    unsigned short hi = f2bf(w);
    unsigned short lo = f2bf(w - bf2f(hi));
    int base = (((s*4+n)*32 + lk*2)*512) + lane*8 + e;
    w1[base] = hi; w1[base+512] = lo;
    return;
  }
  idx -= 524288;
  if (idx < 2048){
    float* bc = (float*)(ws + (idx<1024 ? OFF_BC0 : OFF_BC1));
    int j = idx & 1023;
    bc[j] = (idx<1024) ? (bih0[j]+bhh0[j]) : (bih1[j]+bhh1[j]);
    return;
  }
  idx -= 2048;
  if (idx < 131072){  // zero ring slot 7 (= t-1 at t=0) of both rings
    int* rz = (int*)(ws + (idx<65536 ? OFF_RING0 : OFF_RING1));
    rz[7*65536 + (idx & 65535)] = 0;
    return;
  }
  idx -= 131072;
  if (idx < 256){ out[idx] = 0.f; return; }
  idx -= 256;
  if (idx < 24){ ((int*)(ws + OFF_FLG))[idx] = 0; return; }
}

// ---------------- persistent 2-layer pipeline ----------------
template<int LAYER>
__device__ void run_layer(const float* __restrict__ x, char* __restrict__ ws,
                          const float* __restrict__ Wfc, const float* __restrict__ bfc,
                          float* __restrict__ out, int bg, int sl, char* smem){
  constexpr int HC  = LAYER ? 16 : 9;    // A-chunks per split half
  constexpr int NFR = 2*HC;              // B-frags (lk x {hi,lo})

  unsigned short* Apan = (unsigned short*)smem;            // [32 b][1032] bf16 panel
  float* gatesL = (float*)(smem + 66048);                  // [4 g][16 jl][33]
  float* cstL   = (float*)(smem + 74496);                  // [16 jl][32 b]

  int* f0 = (int*)(ws + OFF_FLG);
  int* f1 = f0 + 8;
  int* r1 = f0 + 16;
  unsigned short* ring0s = (unsigned short*)(ws + OFF_RING0);
  unsigned short* ring1s = (unsigned short*)(ws + OFF_RING1);

  const int tid  = threadIdx.x;
  const int lane = tid & 63;
  const int wv   = tid >> 6;      // wave == gate (i,f,g,o)
  const int m    = lane & 15;
  const int quad = lane >> 4;

  // ---- persistent B-fragments in VGPRs ----
  const unsigned short* wp = (const unsigned short*)(ws + (LAYER ? OFF_W1 : OFF_W0))
                             + ((sl*4 + wv)*NFR)*512 + lane*8;
  v8s bfr[NFR];
  #pragma unroll
  for (int f = 0; f < NFR; ++f) bfr[f] = *(const v8s*)(wp + f*512);

  // ---- per-thread gate-phase constants ----
  const int gb = tid & 31, jp = tid >> 5;
  const float* bcp = (const float*)(ws + (LAYER ? OFF_BC1 : OFF_BC0));
  float bia[2][4];
  #pragma unroll
  for (int p = 0; p < 2; ++p){
    int jl = jp*2 + p;
    #pragma unroll
    for (int g = 0; g < 4; ++g) bia[p][g] = bcp[g*256 + sl*16 + jl];
  }
  float wfcv[2] = {0.f, 0.f};
  if (LAYER == 1){ wfcv[0] = Wfc[sl*16 + jp*2]; wfcv[1] = Wfc[sl*16 + jp*2 + 1]; }
  float fcp = 0.f;

  // zero c-state
  cstL[tid] = 0.f; cstL[tid + 256] = 0.f;
  __syncthreads();

  for (int t = 0; t < TT; ++t){
    // ---- sync waits (tid0 spins, barrier broadcasts) ----
    if (tid == 0){
      if (LAYER == 0){
        if (t > 0)  while (ld_acq(f0 + bg) < 16*t)       __builtin_amdgcn_s_sleep(2);
        if (t >= 8) while (ld_acq(r1 + bg) < 16*(t-7))   __builtin_amdgcn_s_sleep(2);
      } else {
        while (ld_acq(f0 + bg) < 16*(t+1))               __builtin_amdgcn_s_sleep(2);
        if (t > 0) while (ld_acq(f1 + bg) < 16*t)        __builtin_amdgcn_s_sleep(2);
      }
    }
    __syncthreads();

    // ---- stage A-panel (bf16 split) ----
    if (LAYER == 0){
      // k2 layout: [xhi 0..31 | h0hi 32..287 | xlo 288..319 | h0lo 320..575]
      int b = tid >> 3, q = tid & 7;
      float4 xv = *(const float4*)(x + (((bg*32 + b)*TT + t)*32 + q*4));
      u4h hi4, lo4;
      hi4.x = f2bf(xv.x); lo4.x = f2bf(xv.x - bf2f(hi4.x));
      hi4.y = f2bf(xv.y); lo4.y = f2bf(xv.y - bf2f(hi4.y));
      hi4.z = f2bf(xv.z); lo4.z = f2bf(xv.z - bf2f(hi4.z));
      hi4.w = f2bf(xv.w); lo4.w = f2bf(xv.w - bf2f(hi4.w));
      *(u4h*)(Apan + b*1032 + q*4)       = hi4;
      *(u4h*)(Apan + b*1032 + 288 + q*4) = lo4;
      int s = q*64;
      const unsigned short* src = ring0s + (((t+7)&7)*HB + bg*32 + b)*512 + s;
      unsigned short* dp = Apan + b*1032 + ((s < 256) ? (32 + s) : (64 + s));
      #pragma unroll
      for (int i = 0; i < 8; ++i) *(u8h*)(dp + i*8) = *(const u8h*)(src + i*8);
    } else {
      // k2 layout: [h0hi 0..255 | h1hi 256..511 | h0lo 512..767 | h1lo 768..1023]
      int b = tid >> 3, part = tid & 7, s = part*128;
      int rb0 = ((t&7)*HB + bg*32 + b)*512;        // h0[t]
      int rb1 = (((t+7)&7)*HB + bg*32 + b)*512;    // h1[t-1]
      const unsigned short* src; int dst;
      if (part < 2)      { src = ring0s + rb0 + s;         dst = s; }
      else if (part < 4) { src = ring0s + rb0 + s;         dst = s + 256; }
      else if (part < 6) { src = ring1s + rb1 + (s - 512); dst = s - 256; }
      else               { src = ring1s + rb1 + (s - 512); dst = s; }
      unsigned short* dp = Apan + b*1032 + dst;
      #pragma unroll
      for (int i = 0; i < 16; ++i) *(u8h*)(dp + i*8) = *(const u8h*)(src + i*8);
    }
    __syncthreads();
    if (LAYER == 1 && tid == 0) atomicAdd(r1 + bg, 1);   // staged h0[t]: release back-pressure

    // ---- MFMA: gates[b][gc] = sum_k A[b][k] * W[gc][k], 4-product split ----
    v4f acc[2][4];
    #pragma unroll
    for (int i = 0; i < 2; ++i)
      #pragma unroll
      for (int j = 0; j < 4; ++j) acc[i][j] = (v4f){0.f,0.f,0.f,0.f};

    const unsigned short* ap0 = Apan + m*1032;
    const unsigned short* ap1 = Apan + (16+m)*1032;
    #pragma unroll
    for (int c = 0; c < 2*HC; ++c){
      const int lk = (c >= HC) ? (c - HC) : c;
      const int as = (c >= HC) ? 2 : 0;
      v8s A0 = *(const v8s*)(ap0 + c*32 + quad*8);
      v8s A1 = *(const v8s*)(ap1 + c*32 + quad*8);
      v8s B0 = bfr[lk*2+0];
      v8s B1 = bfr[lk*2+1];
      acc[0][as+0] = __builtin_amdgcn_mfma_f32_16x16x32_bf16(A0,B0,acc[0][as+0],0,0,0);
      acc[0][as+1] = __builtin_amdgcn_mfma_f32_16x16x32_bf16(A0,B1,acc[0][as+1],0,0,0);
      acc[1][as+0] = __builtin_amdgcn_mfma_f32_16x16x32_bf16(A1,B0,acc[1][as+0],0,0,0);
      acc[1][as+1] = __builtin_amdgcn_mfma_f32_16x16x32_bf16(A1,B1,acc[1][as+1],0,0,0);
    }
    {
      v4f s0 = acc[0][0]+acc[0][1]+acc[0][2]+acc[0][3];
      v4f s1 = acc[1][0]+acc[1][1]+acc[1][2]+acc[1][3];
      int cn = lane & 15;   // C col = jl
      #pragma unroll
      for (int r = 0; r < 4; ++r){   // C row = quad*4+r = b
        gatesL[wv*528 + cn*33 + (quad*4 + r)]        = s0[r];
        gatesL[wv*528 + cn*33 + 16 + (quad*4 + r)]   = s1[r];
      }
    }
    __syncthreads();

    // ---- gate nonlinearity + state update + ring write ----
    {
      float hloc[2];
      #pragma unroll
      for (int p = 0; p < 2; ++p){
        int jl = jp*2 + p;
        float gi = gatesL[0*528 + jl*33 + gb] + bia[p][0];
        float gf = gatesL[1*528 + jl*33 + gb] + bia[p][1];
        float gg = gatesL[2*528 + jl*33 + gb] + bia[p][2];
        float go = gatesL[3*528 + jl*33 + gb] + bia[p][3];
        float iv = sigm(gi), fv = sigm(gf), gv = tanh_(gg), ov = sigm(go);
        float c = fv*cstL[jl*32 + gb] + iv*gv;
        cstL[jl*32 + gb] = c;
        float h = ov*tanh_(c);
        hloc[p] = h;
        unsigned short hh = f2bf(h);
        unsigned short hl = f2bf(h - bf2f(hh));
        unsigned short* rw = (LAYER ? ring1s : ring0s)
                             + ((t&7)*HB + bg*32 + gb)*512 + (sl*16 + jl);
        rw[0] = hh; rw[256] = hl;
      }
      if (LAYER == 1 && t == TT-1) fcp = hloc[0]*wfcv[0] + hloc[1]*wfcv[1];
    }
    __threadfence();
    __syncthreads();
    if (tid == 0) atomicAdd((LAYER ? f1 : f0) + bg, 1);
  }

  // ---- FC epilogue (layer1) ----
  if (LAYER == 1){
    __syncthreads();
    float* red = gatesL;
    red[tid] = fcp;
    __syncthreads();
    if (tid < 32){
      float sm = 0.f;
      #pragma unroll
      for (int q = 0; q < 8; ++q) sm += red[q*32 + tid];
      if (sl == 0) sm += bfc[0];
      atomicAdd(&out[bg*32 + tid], sm);
    }
  }
}

__global__ __launch_bounds__(256,1) void lstm_pipe(const float* __restrict__ x, char* __restrict__ ws,
                                                   const float* __restrict__ Wfc, const float* __restrict__ bfc,
                                                   float* __restrict__ out){
  extern __shared__ __align__(16) char smem[];
  int bid = blockIdx.x;
  if (bid < 128) run_layer<0>(x, ws, Wfc, bfc, out, bid & 7, bid >> 3, smem);
  else { int lb = bid - 128; run_layer<1>(x, ws, Wfc, bfc, out, lb & 7, lb >> 3, smem); }
}

extern "C" void kernel_launch(void* const* d_in, const int* in_sizes, int n_in,
                              void* d_out, int out_size, void* d_ws, size_t ws_size,
                              hipStream_t stream) {
  const float* x    = (const float*)d_in[0];
  const float* Wih0 = (const float*)d_in[1];
  const float* Whh0 = (const float*)d_in[2];
  const float* bih0 = (const float*)d_in[3];
  const float* bhh0 = (const float*)d_in[4];
  const float* Wih1 = (const float*)d_in[5];
  const float* Whh1 = (const float*)d_in[6];
  const float* bih1 = (const float*)d_in[7];
  const float* bhh1 = (const float*)d_in[8];
  const float* Wfc  = (const float*)d_in[9];
  const float* bfc  = (const float*)d_in[10];
  float* out = (float*)d_out;
  char* ws   = (char*)d_ws;
  (void)in_sizes; (void)n_in; (void)out_size; (void)ws_size;

  pack_all<<<3722, 256, 0, stream>>>(Wih0, Whh0, bih0, bhh0, Wih1, Whh1, bih1, bhh1, ws, out);
  lstm_pipe<<<256, 256, SMEM_BYTES, stream>>>(x, ws, Wfc, bfc, out);
}

// Round 5
// 12884.604 us; speedup vs baseline: 2.6521x; 1.8966x over previous
//
#include <hip/hip_runtime.h>

// LSTMForecast: B=256, T=512, IN=32, H=256, OUT=1, fp32.
// Round 5: weight-stationary split-bf16 MFMA, contention-free sync.
//   - 128 persistent blocks: bid = bg*16 + layer*8 + sl  (8 bg x 2 layers x 8 j-slices of 32).
//   - Weights (bf16 hi+lo exact split) resident in VGPRs (~256/lane for layer1).
//   - Per-writer flag words (release stores, no atomic RMW), 128B line per (layer,bg).
//   - Rings slice-major: coalesced 16B writes; staging in 16B units, <=2-way LDS banks.
//   - 4-product split MFMA (hi*hi + hi*lo + lo*hi + lo*lo) => fp32-grade accuracy.

#define TT 512

typedef short v8s __attribute__((ext_vector_type(8)));
typedef float v4f __attribute__((ext_vector_type(4)));
typedef unsigned short u4h __attribute__((ext_vector_type(4)));
typedef unsigned short u8h __attribute__((ext_vector_type(8)));

// ws byte offsets
constexpr size_t OFF_W0    = 0;          // 1,179,648 B  [sl][g][jc][kc 9][spl][512 sh]
constexpr size_t OFF_W1    = 1179648;    // 2,097,152 B  [sl][g][jc][kc 16][spl][512 sh]
constexpr size_t OFF_BC0   = 3276800;    // 4096 B
constexpr size_t OFF_BC1   = 3280896;    // 4096 B
constexpr size_t OFF_FLG   = 3284992;    // 2048 B: 16 lines x 128B; line L*8+bg, word sl
constexpr size_t OFF_RING0 = 3287040;    // 8 slot x 256 b x 512 sh (slice-major: [sl][hi32|lo32])
constexpr size_t OFF_RING1 = 5384192;    // same; end 7,481,344

__device__ __forceinline__ float bf2f(unsigned short h){ return __uint_as_float(((unsigned)h)<<16); }
__device__ __forceinline__ unsigned short f2bf(float f){
  unsigned u = __float_as_uint(f);
  u += 0x7FFF + ((u>>16)&1);
  return (unsigned short)(u>>16);
}
__device__ __forceinline__ float sigm(float v){ return 1.0f/(1.0f + expf(-v)); }
__device__ __forceinline__ float tanh_(float v){
  float a = fabsf(v);
  float e = expf(-2.0f*a);
  float r = (1.0f - e)/(1.0f + e);
  return copysignf(r, v);
}
__device__ __forceinline__ int ld_rlx(const int* p){
  return __hip_atomic_load(p, __ATOMIC_RELAXED, __HIP_MEMORY_SCOPE_AGENT);
}
__device__ __forceinline__ void st_rel(int* p, int v){
  __hip_atomic_store(p, v, __ATOMIC_RELEASE, __HIP_MEMORY_SCOPE_AGENT);
}
__device__ __forceinline__ int minflags(const int* line){
  int m = 0x7fffffff;
  #pragma unroll
  for (int s = 0; s < 8; ++s){ int v = ld_rlx(line + s); m = v < m ? v : m; }
  return m;
}

// ---------------- pack kernel ----------------
__global__ void pack_all(const float* __restrict__ Wih0, const float* __restrict__ Whh0,
                         const float* __restrict__ bih0, const float* __restrict__ bhh0,
                         const float* __restrict__ Wih1, const float* __restrict__ Whh1,
                         const float* __restrict__ bih1, const float* __restrict__ bhh1,
                         char* __restrict__ ws, float* __restrict__ out){
  int idx = blockIdx.x*256 + threadIdx.x;
  if (idx < 589824){    // W0 shorts
    int e = idx&7, lane = (idx>>3)&63, r = idx>>9;
    int spl = r&1, t1 = r>>1;
    int kc = t1%9, t2 = t1/9;
    int jc = t2&1, g = (t2>>1)&3, sl = t2>>3;
    int row = g*256 + sl*32 + jc*16 + (lane&15);
    int k = kc*32 + (lane>>4)*8 + e;
    float w = (k < 32) ? Wih0[row*32 + k] : Whh0[row*256 + (k-32)];
    unsigned short hi = f2bf(w);
    unsigned short v = spl ? f2bf(w - bf2f(hi)) : hi;
    ((unsigned short*)(ws + OFF_W0))[idx] = v;
    return;
  }
  idx -= 589824;
  if (idx < 1048576){   // W1 shorts
    int e = idx&7, lane = (idx>>3)&63, r = idx>>9;
    int spl = r&1, t1 = r>>1;
    int kc = t1&15, t2 = t1>>4;
    int jc = t2&1, g = (t2>>1)&3, sl = t2>>3;
    int row = g*256 + sl*32 + jc*16 + (lane&15);
    int k = kc*32 + (lane>>4)*8 + e;
    float w = (k < 256) ? Wih1[row*256 + k] : Whh1[row*256 + (k-256)];
    unsigned short hi = f2bf(w);
    unsigned short v = spl ? f2bf(w - bf2f(hi)) : hi;
    ((unsigned short*)(ws + OFF_W1))[idx] = v;
    return;
  }
  idx -= 1048576;
  if (idx < 2048){      // combined biases
    float* bc = (float*)(ws + (idx < 1024 ? OFF_BC0 : OFF_BC1));
    int j = idx & 1023;
    bc[j] = (idx < 1024) ? (bih0[j]+bhh0[j]) : (bih1[j]+bhh1[j]);
    return;
  }
  idx -= 2048;
  if (idx < 131072){    // zero ring slot 7 (h[-1]) of both rings
    int* rz = (int*)(ws + (idx < 65536 ? OFF_RING0 : OFF_RING1) + (size_t)7*262144);
    rz[idx & 65535] = 0;
    return;
  }
  idx -= 131072;
  if (idx < 256){ out[idx] = 0.f; return; }
  idx -= 256;
  if (idx < 512){ ((int*)(ws + OFF_FLG))[idx] = 0; return; }
}

// ---------------- persistent layer worker ----------------
template<int LAYER>
__device__ void run_layer(const float* __restrict__ x, char* __restrict__ ws,
                          const float* __restrict__ Wfc, const float* __restrict__ bfc,
                          float* __restrict__ out, int bg, int sl,
                          unsigned short* Apan, float* gatesL, float* cst, unsigned short* hbuf){
  constexpr int NKC = LAYER ? 16 : 9;    // k-chunks per split half
  constexpr int NCH = 2*NKC;             // A chunks (hi then lo)
  constexpr int NFR = 4*NKC;             // B frags per wave: [jc2][kc][spl2]

  int* flg = (int*)(ws + OFF_FLG);
  int* f0line = flg + bg*32;
  int* f1line = flg + (8 + bg)*32;
  unsigned short* ring0 = (unsigned short*)(ws + OFF_RING0);
  unsigned short* ring1 = (unsigned short*)(ws + OFF_RING1);

  const int tid  = threadIdx.x;
  const int lane = tid & 63;
  const int wv   = tid >> 6;       // wave == gate
  const int m    = lane & 15;
  const int quad = lane >> 4;

  // ---- persistent B-fragments ----
  const unsigned short* wp = (const unsigned short*)(ws + (LAYER ? OFF_W1 : OFF_W0))
                             + (size_t)(sl*4 + wv)*NFR*512 + lane*8;
  v8s bfr[NFR];
  #pragma unroll
  for (int f = 0; f < NFR; ++f) bfr[f] = *(const v8s*)(wp + f*512);

  // ---- gate-phase constants ----
  const int bb = tid & 31, jq = tid >> 5;          // thread owns (b=bb, j = jq*4..+4)
  const float* bcp = (const float*)(ws + (LAYER ? OFF_BC1 : OFF_BC0));
  float bia[4][4];
  #pragma unroll
  for (int p = 0; p < 4; ++p)
    #pragma unroll
    for (int g = 0; g < 4; ++g) bia[p][g] = bcp[g*256 + sl*32 + jq*4 + p];
  float wfcv[4] = {0.f,0.f,0.f,0.f};
  if (LAYER == 1){
    #pragma unroll
    for (int p = 0; p < 4; ++p) wfcv[p] = Wfc[sl*32 + jq*4 + p];
  }
  float fcp = 0.f;

  // zero c-state
  for (int i = tid; i < 1056; i += 256) cst[i] = 0.f;
  __syncthreads();

  const int b8 = tid >> 3, sub = tid & 7;          // staging/copy-out roles
  int kn0 = 0, kn1 = 0;                            // cached flag minima (tid0)

  for (int t = 0; t < TT; ++t){
    // ---- x prefetch (layer0), in flight across the wait ----
    float4 xv;
    if (LAYER == 0)
      xv = *(const float4*)(x + ((size_t)(bg*32 + b8)*TT + t)*32 + sub*4);

    // ---- waits: per-writer flag words, no RMW ----
    if (tid == 0){
      int need0 = LAYER ? (t+1) : t;               // completed-step counts
      int need1 = LAYER ? t : (t-7);
      if (kn0 < need0) while ((kn0 = minflags(f0line)) < need0) __builtin_amdgcn_s_sleep(2);
      if (need1 > 0 && kn1 < need1) while ((kn1 = minflags(f1line)) < need1) __builtin_amdgcn_s_sleep(2);
    }
    __syncthreads();                               // B1
    __builtin_amdgcn_fence(__ATOMIC_ACQUIRE, "agent");  // invalidate L1: fresh ring reads

    // ---- stage A-panel (16B units, <=2-way banks) ----
    unsigned short* arow = Apan + b8*1032;
    if (LAYER == 0){
      u4h hi4, lo4;
      hi4.x = f2bf(xv.x); lo4.x = f2bf(xv.x - bf2f(hi4.x));
      hi4.y = f2bf(xv.y); lo4.y = f2bf(xv.y - bf2f(hi4.y));
      hi4.z = f2bf(xv.z); lo4.z = f2bf(xv.z - bf2f(hi4.z));
      hi4.w = f2bf(xv.w); lo4.w = f2bf(xv.w - bf2f(hi4.w));
      *(u4h*)(arow + sub*4)       = hi4;           // x hi: shorts 0..31
      *(u4h*)(arow + 288 + sub*4) = lo4;           // x lo: 288..319
      const unsigned short* r0row = ring0 + ((size_t)(((t+7)&7)*256 + bg*32 + b8))*512;
      #pragma unroll
      for (int i = 0; i < 8; ++i){
        int q = i*8 + sub;
        const unsigned short* src; unsigned short* dst;
        if (q < 32){ src = r0row + (q>>2)*64 + (q&3)*8;        dst = arow + 32  + q*8; }
        else { int r2 = q-32; src = r0row + (r2>>2)*64 + 32 + (r2&3)*8; dst = arow + 320 + r2*8; }
        *(u8h*)dst = *(const u8h*)src;
      }
    } else {
      const unsigned short* r0row = ring0 + ((size_t)((t&7)*256 + bg*32 + b8))*512;       // h0[t]
      const unsigned short* r1row = ring1 + ((size_t)(((t+7)&7)*256 + bg*32 + b8))*512;   // h1[t-1]
      #pragma unroll
      for (int i = 0; i < 16; ++i){
        int q = i*8 + sub;
        const unsigned short* src; unsigned short* dst;
        if (q < 32)      { src = r0row + (q>>2)*64 + (q&3)*8;               dst = arow + q*8; }           // h0 hi -> 0..255
        else if (q < 64) { int r2=q-32; src = r0row + (r2>>2)*64+32+(r2&3)*8; dst = arow + 512 + r2*8; }  // h0 lo -> 512..767
        else if (q < 96) { int p2=q-64; src = r1row + (p2>>2)*64+(p2&3)*8;    dst = arow + 256 + p2*8; }  // h1 hi -> 256..511
        else             { int r2=q-96; src = r1row + (r2>>2)*64+32+(r2&3)*8; dst = arow + 768 + r2*8; }  // h1 lo -> 768..1023
        *(u8h*)dst = *(const u8h*)src;
      }
    }
    __syncthreads();                               // B2: Apan ready

    // ---- MFMA: 4-product split, C-tile 32b x 32j per wave ----
    v4f a00={0,0,0,0}, a01={0,0,0,0}, a10={0,0,0,0}, a11={0,0,0,0};
    const unsigned short* ap0 = Apan + m*1032 + quad*8;
    const unsigned short* ap1 = ap0 + 16*1032;
    #pragma unroll
    for (int c = 0; c < NCH; ++c){
      const int kc  = (c < NKC) ? c : (c - NKC);
      const int spl = (c < NKC) ? 0 : 1;           // A half
      v8s A0 = *(const v8s*)(ap0 + c*32);
      v8s A1 = *(const v8s*)(ap1 + c*32);
      v8s B0h = bfr[(kc)*2 + 0],        B0l = bfr[(kc)*2 + 1];          // jc=0
      v8s B1h = bfr[(NKC + kc)*2 + 0],  B1l = bfr[(NKC + kc)*2 + 1];    // jc=1
      (void)spl;
      a00 = __builtin_amdgcn_mfma_f32_16x16x32_bf16(A0, B0h, a00, 0,0,0);
      a00 = __builtin_amdgcn_mfma_f32_16x16x32_bf16(A0, B0l, a00, 0,0,0);
      a01 = __builtin_amdgcn_mfma_f32_16x16x32_bf16(A0, B1h, a01, 0,0,0);
      a01 = __builtin_amdgcn_mfma_f32_16x16x32_bf16(A0, B1l, a01, 0,0,0);
      a10 = __builtin_amdgcn_mfma_f32_16x16x32_bf16(A1, B0h, a10, 0,0,0);
      a10 = __builtin_amdgcn_mfma_f32_16x16x32_bf16(A1, B0l, a10, 0,0,0);
      a11 = __builtin_amdgcn_mfma_f32_16x16x32_bf16(A1, B1h, a11, 0,0,0);
      a11 = __builtin_amdgcn_mfma_f32_16x16x32_bf16(A1, B1l, a11, 0,0,0);
    }
    // C store: col=lane&15 -> j-within-16, row=quad*4+r -> b-within-16 (R4-verified)
    {
      const int col = m, rb = quad*4;
      float* gw = gatesL + wv*1056;
      #pragma unroll
      for (int r = 0; r < 4; ++r){
        gw[(col)*33      + rb + r]      = a00[r];
        gw[(16+col)*33   + rb + r]      = a01[r];
        gw[(col)*33      + 16 + rb + r] = a10[r];
        gw[(16+col)*33   + 16 + rb + r] = a11[r];
      }
    }
    __syncthreads();                               // B3: gates ready

    // ---- gate nonlinearity + state + hbuf ----
    {
      float fa = 0.f;
      #pragma unroll
      for (int p = 0; p < 4; ++p){
        int jl = jq*4 + p;
        float gi = gatesL[0*1056 + jl*33 + bb] + bia[p][0];
        float gf = gatesL[1*1056 + jl*33 + bb] + bia[p][1];
        float gg = gatesL[2*1056 + jl*33 + bb] + bia[p][2];
        float go = gatesL[3*1056 + jl*33 + bb] + bia[p][3];
        float iv = sigm(gi), fv = sigm(gf), gv = tanh_(gg), ov = sigm(go);
        float cc = fv*cst[jl*33 + bb] + iv*gv;
        cst[jl*33 + bb] = cc;
        float h = ov*tanh_(cc);
        unsigned short hh = f2bf(h);
        unsigned short hl = f2bf(h - bf2f(hh));
        hbuf[bb*72 + jl]      = hh;
        hbuf[bb*72 + 32 + jl] = hl;
        if (LAYER == 1) fa = fmaf(h, wfcv[p], fa);
      }
      if (LAYER == 1 && t == TT-1) fcp = fa;
    }
    __syncthreads();                               // B4: hbuf ready

    // ---- ring write: one 16B store per thread, slice-contiguous ----
    {
      unsigned short* rw = (LAYER ? ring1 : ring0)
                           + ((size_t)((t&7)*256 + bg*32 + b8))*512 + sl*64 + sub*8;
      *(u8h*)rw = *(const u8h*)(hbuf + b8*72 + sub*8);
    }
    __threadfence();
    __syncthreads();                               // B5: all ring writes fenced
    if (tid == 0) st_rel((LAYER ? f1line : f0line) + sl, t+1);
  }

  // ---- FC epilogue ----
  if (LAYER == 1){
    __syncthreads();
    float* red = gatesL;
    red[tid] = fcp;
    __syncthreads();
    if (tid < 32){
      float sm = 0.f;
      #pragma unroll
      for (int q = 0; q < 8; ++q) sm += red[q*32 + tid];
      if (sl == 0) sm += bfc[0];
      atomicAdd(&out[bg*32 + tid], sm);
    }
  }
}

__global__ __launch_bounds__(256,1) void lstm_pipe(const float* __restrict__ x, char* __restrict__ ws,
                                                   const float* __restrict__ Wfc, const float* __restrict__ bfc,
                                                   float* __restrict__ out){
  __shared__ unsigned short Apan[32*1032];   // 66,048 B
  __shared__ float gatesL[4224];             // 16,896 B [4 g][32 j][33]
  __shared__ float cst[1056];                //  4,224 B [32 j][33]
  __shared__ unsigned short hbuf[32*72];     //  4,608 B [32 b][hi32|lo32|pad8]
  const int bid = blockIdx.x;
  const int bg = bid >> 4, rem = bid & 15, layer = rem >> 3, sl = rem & 7;
  if (layer == 0) run_layer<0>(x, ws, Wfc, bfc, out, bg, sl, Apan, gatesL, cst, hbuf);
  else            run_layer<1>(x, ws, Wfc, bfc, out, bg, sl, Apan, gatesL, cst, hbuf);
}

extern "C" void kernel_launch(void* const* d_in, const int* in_sizes, int n_in,
                              void* d_out, int out_size, void* d_ws, size_t ws_size,
                              hipStream_t stream) {
  const float* x    = (const float*)d_in[0];
  const float* Wih0 = (const float*)d_in[1];
  const float* Whh0 = (const float*)d_in[2];
  const float* bih0 = (const float*)d_in[3];
  const float* bhh0 = (const float*)d_in[4];
  const float* Wih1 = (const float*)d_in[5];
  const float* Whh1 = (const float*)d_in[6];
  const float* bih1 = (const float*)d_in[7];
  const float* bhh1 = (const float*)d_in[8];
  const float* Wfc  = (const float*)d_in[9];
  const float* bfc  = (const float*)d_in[10];
  float* out = (float*)d_out;
  char* ws   = (char*)d_ws;
  (void)in_sizes; (void)n_in; (void)out_size; (void)ws_size;

  // total pack items: 589824+1048576+2048+131072+256+512 = 1,772,288 = 6923*256
  pack_all<<<6923, 256, 0, stream>>>(Wih0, Whh0, bih0, bhh0, Wih1, Whh1, bih1, bhh1, ws, out);
  lstm_pipe<<<128, 256, 0, stream>>>(x, ws, Wfc, bfc, out);
}

// Round 6
// 7017.426 us; speedup vs baseline: 4.8696x; 1.8361x over previous
//
#include <hip/hip_runtime.h>

// LSTMForecast: B=256, T=512, IN=32, H=256, OUT=1, fp32.
// Round 6: fence-free cross-block sync (relaxed agent atomics only).
//   - R5 structure: 128 blocks = 8 bg x 2 layers x 8 j-slices; weights (bf16 hi+lo
//     exact split) resident in VGPRs; 4-product split MFMA = fp32-grade accuracy.
//   - NO fences (R5's agent acquire fence = per-step L2 invalidate -> 1.1 GB refetch).
//     Ring + flags accessed via relaxed agent-scope atomics (global_*_dword sc0 sc1):
//     bypass L1/L2, hit die-level coherence point; order via s_waitcnt vmcnt(0)+barrier.
//   - bid = sl*16 + layer*8 + bg: bg-cluster per XCD under round-robin (perf only).

#define TT 512

typedef short v8s __attribute__((ext_vector_type(8)));
typedef float v4f __attribute__((ext_vector_type(4)));
typedef unsigned short u4h __attribute__((ext_vector_type(4)));

// ws byte offsets
constexpr size_t OFF_W0    = 0;          // 1,179,648 B  [sl][g][jc][kc 9][spl][512 sh]
constexpr size_t OFF_W1    = 1179648;    // 2,097,152 B  [sl][g][jc][kc 16][spl][512 sh]
constexpr size_t OFF_BC0   = 3276800;    // 4096 B
constexpr size_t OFF_BC1   = 3280896;    // 4096 B
constexpr size_t OFF_FLG   = 3284992;    // 2048 B: 16 lines x 128B; line L*8+bg, word sl
constexpr size_t OFF_RING0 = 3287040;    // 8 slot x 256 b x 512 sh (row: [sl 8][hi32|lo32])
constexpr size_t OFF_RING1 = 5384192;    // same; end 7,481,344

__device__ __forceinline__ float bf2f(unsigned short h){ return __uint_as_float(((unsigned)h)<<16); }
__device__ __forceinline__ unsigned short f2bf(float f){
  unsigned u = __float_as_uint(f);
  u += 0x7FFF + ((u>>16)&1);
  return (unsigned short)(u>>16);
}
__device__ __forceinline__ float sigm(float v){ return 1.0f/(1.0f + expf(-v)); }
__device__ __forceinline__ float tanh_(float v){
  float a = fabsf(v);
  float e = expf(-2.0f*a);
  float r = (1.0f - e)/(1.0f + e);
  return copysignf(r, v);
}
// relaxed agent-scope atomics: lower to global_load/store_dword sc0 sc1 (L1/L2 bypass,
// served at die-level coherence point). No cache-maintenance instructions emitted.
__device__ __forceinline__ int ld_flag(const int* p){
  return __hip_atomic_load(p, __ATOMIC_RELAXED, __HIP_MEMORY_SCOPE_AGENT);
}
__device__ __forceinline__ void st_flag(int* p, int v){
  __hip_atomic_store(p, v, __ATOMIC_RELAXED, __HIP_MEMORY_SCOPE_AGENT);
}
__device__ __forceinline__ unsigned ld_ring(const unsigned* p){
  return __hip_atomic_load(p, __ATOMIC_RELAXED, __HIP_MEMORY_SCOPE_AGENT);
}
__device__ __forceinline__ void st_ring(unsigned* p, unsigned v){
  __hip_atomic_store(p, v, __ATOMIC_RELAXED, __HIP_MEMORY_SCOPE_AGENT);
}
__device__ __forceinline__ int minflags(const int* line){
  int m = 0x7fffffff;
  #pragma unroll
  for (int s = 0; s < 8; ++s){ int v = ld_flag(line + s); m = v < m ? v : m; }
  return m;
}

// ---------------- pack kernel (unchanged from R5) ----------------
__global__ void pack_all(const float* __restrict__ Wih0, const float* __restrict__ Whh0,
                         const float* __restrict__ bih0, const float* __restrict__ bhh0,
                         const float* __restrict__ Wih1, const float* __restrict__ Whh1,
                         const float* __restrict__ bih1, const float* __restrict__ bhh1,
                         char* __restrict__ ws, float* __restrict__ out){
  int idx = blockIdx.x*256 + threadIdx.x;
  if (idx < 589824){    // W0 shorts
    int e = idx&7, lane = (idx>>3)&63, r = idx>>9;
    int spl = r&1, t1 = r>>1;
    int kc = t1%9, t2 = t1/9;
    int jc = t2&1, g = (t2>>1)&3, sl = t2>>3;
    int row = g*256 + sl*32 + jc*16 + (lane&15);
    int k = kc*32 + (lane>>4)*8 + e;
    float w = (k < 32) ? Wih0[row*32 + k] : Whh0[row*256 + (k-32)];
    unsigned short hi = f2bf(w);
    unsigned short v = spl ? f2bf(w - bf2f(hi)) : hi;
    ((unsigned short*)(ws + OFF_W0))[idx] = v;
    return;
  }
  idx -= 589824;
  if (idx < 1048576){   // W1 shorts
    int e = idx&7, lane = (idx>>3)&63, r = idx>>9;
    int spl = r&1, t1 = r>>1;
    int kc = t1&15, t2 = t1>>4;
    int jc = t2&1, g = (t2>>1)&3, sl = t2>>3;
    int row = g*256 + sl*32 + jc*16 + (lane&15);
    int k = kc*32 + (lane>>4)*8 + e;
    float w = (k < 256) ? Wih1[row*256 + k] : Whh1[row*256 + (k-256)];
    unsigned short hi = f2bf(w);
    unsigned short v = spl ? f2bf(w - bf2f(hi)) : hi;
    ((unsigned short*)(ws + OFF_W1))[idx] = v;
    return;
  }
  idx -= 1048576;
  if (idx < 2048){      // combined biases
    float* bc = (float*)(ws + (idx < 1024 ? OFF_BC0 : OFF_BC1));
    int j = idx & 1023;
    bc[j] = (idx < 1024) ? (bih0[j]+bhh0[j]) : (bih1[j]+bhh1[j]);
    return;
  }
  idx -= 2048;
  if (idx < 131072){    // zero ring slot 7 (h[-1]) of both rings
    int* rz = (int*)(ws + (idx < 65536 ? OFF_RING0 : OFF_RING1) + (size_t)7*262144);
    rz[idx & 65535] = 0;
    return;
  }
  idx -= 131072;
  if (idx < 256){ out[idx] = 0.f; return; }
  idx -= 256;
  if (idx < 512){ ((int*)(ws + OFF_FLG))[idx] = 0; return; }
}

// ---------------- persistent layer worker ----------------
template<int LAYER>
__device__ void run_layer(const float* __restrict__ x, char* __restrict__ ws,
                          const float* __restrict__ Wfc, const float* __restrict__ bfc,
                          float* __restrict__ out, int bg, int sl,
                          unsigned short* Apan, float* gatesL, float* cst, unsigned short* hbuf){
  constexpr int NKC = LAYER ? 16 : 9;    // k-chunks per split half
  constexpr int NCH = 2*NKC;             // A chunks (hi then lo)
  constexpr int NFR = 4*NKC;             // B frags per wave: [jc2][kc][spl2]

  int* flg = (int*)(ws + OFF_FLG);
  int* f0line = flg + bg*32;
  int* f1line = flg + (8 + bg)*32;
  unsigned short* ring0 = (unsigned short*)(ws + OFF_RING0);
  unsigned short* ring1 = (unsigned short*)(ws + OFF_RING1);

  const int tid  = threadIdx.x;
  const int lane = tid & 63;
  const int wv   = tid >> 6;       // wave == gate
  const int m    = lane & 15;
  const int quad = lane >> 4;

  // ---- persistent B-fragments ----
  const unsigned short* wp = (const unsigned short*)(ws + (LAYER ? OFF_W1 : OFF_W0))
                             + (size_t)(sl*4 + wv)*NFR*512 + lane*8;
  v8s bfr[NFR];
  #pragma unroll
  for (int f = 0; f < NFR; ++f) bfr[f] = *(const v8s*)(wp + f*512);

  // ---- gate-phase constants ----
  const int bb = tid & 31, jq = tid >> 5;          // thread owns (b=bb, j = jq*4..+4)
  const float* bcp = (const float*)(ws + (LAYER ? OFF_BC1 : OFF_BC0));
  float bia[4][4];
  #pragma unroll
  for (int p = 0; p < 4; ++p)
    #pragma unroll
    for (int g = 0; g < 4; ++g) bia[p][g] = bcp[g*256 + sl*32 + jq*4 + p];
  float wfcv[4] = {0.f,0.f,0.f,0.f};
  if (LAYER == 1){
    #pragma unroll
    for (int p = 0; p < 4; ++p) wfcv[p] = Wfc[sl*32 + jq*4 + p];
  }
  float fcp = 0.f;

  // zero c-state
  for (int i = tid; i < 1056; i += 256) cst[i] = 0.f;
  __syncthreads();

  const int b8 = tid >> 3, sub = tid & 7;          // staging/copy-out roles
  int kn0 = 0, kn1 = 0;                            // cached flag minima (tid0)

  for (int t = 0; t < TT; ++t){
    // ---- x prefetch (layer0), in flight across the wait ----
    float4 xv;
    if (LAYER == 0)
      xv = *(const float4*)(x + ((size_t)(bg*32 + b8)*TT + t)*32 + sub*4);

    // ---- waits: per-writer flag words, relaxed agent loads, no RMW/fence ----
    if (tid == 0){
      int need0 = LAYER ? (t+1) : t;               // completed-step counts
      int need1 = LAYER ? t : (t-7);
      if (kn0 < need0) while ((kn0 = minflags(f0line)) < need0) __builtin_amdgcn_s_sleep(2);
      if (need1 > 0 && kn1 < need1) while ((kn1 = minflags(f1line)) < need1) __builtin_amdgcn_s_sleep(2);
    }
    __syncthreads();                               // B1 (no acquire fence needed:
                                                   //     ring loads below bypass caches)

    // ---- stage A-panel (dword agent-scope loads -> LDS) ----
    unsigned short* arow = Apan + b8*1032;
    unsigned* arowdw = (unsigned*)arow;
    if (LAYER == 0){
      u4h hi4, lo4;
      hi4.x = f2bf(xv.x); lo4.x = f2bf(xv.x - bf2f(hi4.x));
      hi4.y = f2bf(xv.y); lo4.y = f2bf(xv.y - bf2f(hi4.y));
      hi4.z = f2bf(xv.z); lo4.z = f2bf(xv.z - bf2f(hi4.z));
      hi4.w = f2bf(xv.w); lo4.w = f2bf(xv.w - bf2f(hi4.w));
      *(u4h*)(arow + sub*4)       = hi4;           // x hi: shorts 0..31  (dw 0..15)
      *(u4h*)(arow + 288 + sub*4) = lo4;           // x lo: 288..319     (dw 144..159)
      const unsigned* r0dw = (const unsigned*)(ring0 + ((size_t)(((t+7)&7)*256 + bg*32 + b8))*512);
      #pragma unroll
      for (int i = 0; i < 32; ++i){
        int d = i*8 + sub;                         // 0..255 dwords of ring row
        unsigned v = ld_ring(r0dw + d);
        int sl2 = d >> 5, wd = d & 31;
        int dst = (wd < 16) ? (16 + sl2*16 + wd)         // h0 hi -> dw 16..143
                            : (160 + sl2*16 + (wd-16));  // h0 lo -> dw 160..287
        arowdw[dst] = v;
      }
    } else {
      const unsigned* r0dw = (const unsigned*)(ring0 + ((size_t)((t&7)*256 + bg*32 + b8))*512);     // h0[t]
      const unsigned* r1dw = (const unsigned*)(ring1 + ((size_t)(((t+7)&7)*256 + bg*32 + b8))*512); // h1[t-1]
      #pragma unroll
      for (int i = 0; i < 32; ++i){
        int d = i*8 + sub;
        unsigned v = ld_ring(r0dw + d);
        int sl2 = d >> 5, wd = d & 31;
        int dst = (wd < 16) ? (sl2*16 + wd)              // h0 hi -> dw 0..127
                            : (256 + sl2*16 + (wd-16));  // h0 lo -> dw 256..383
        arowdw[dst] = v;
      }
      #pragma unroll
      for (int i = 0; i < 32; ++i){
        int d = i*8 + sub;
        unsigned v = ld_ring(r1dw + d);
        int sl2 = d >> 5, wd = d & 31;
        int dst = (wd < 16) ? (128 + sl2*16 + wd)        // h1 hi -> dw 128..255
                            : (384 + sl2*16 + (wd-16));  // h1 lo -> dw 384..511
        arowdw[dst] = v;
      }
    }
    __syncthreads();                               // B2: Apan ready

    // ---- MFMA: 4-product split, C-tile 32b x 32j per wave ----
    v4f a00={0,0,0,0}, a01={0,0,0,0}, a10={0,0,0,0}, a11={0,0,0,0};
    const unsigned short* ap0 = Apan + m*1032 + quad*8;
    const unsigned short* ap1 = ap0 + 16*1032;
    #pragma unroll
    for (int c = 0; c < NCH; ++c){
      const int kc  = (c < NKC) ? c : (c - NKC);
      v8s A0 = *(const v8s*)(ap0 + c*32);
      v8s A1 = *(const v8s*)(ap1 + c*32);
      v8s B0h = bfr[(kc)*2 + 0],        B0l = bfr[(kc)*2 + 1];          // jc=0
      v8s B1h = bfr[(NKC + kc)*2 + 0],  B1l = bfr[(NKC + kc)*2 + 1];    // jc=1
      a00 = __builtin_amdgcn_mfma_f32_16x16x32_bf16(A0, B0h, a00, 0,0,0);
      a00 = __builtin_amdgcn_mfma_f32_16x16x32_bf16(A0, B0l, a00, 0,0,0);
      a01 = __builtin_amdgcn_mfma_f32_16x16x32_bf16(A0, B1h, a01, 0,0,0);
      a01 = __builtin_amdgcn_mfma_f32_16x16x32_bf16(A0, B1l, a01, 0,0,0);
      a10 = __builtin_amdgcn_mfma_f32_16x16x32_bf16(A1, B0h, a10, 0,0,0);
      a10 = __builtin_amdgcn_mfma_f32_16x16x32_bf16(A1, B0l, a10, 0,0,0);
      a11 = __builtin_amdgcn_mfma_f32_16x16x32_bf16(A1, B1h, a11, 0,0,0);
      a11 = __builtin_amdgcn_mfma_f32_16x16x32_bf16(A1, B1l, a11, 0,0,0);
    }
    // C store: col=lane&15 -> j-within-16, row=quad*4+r -> b-within-16
    {
      const int col = m, rb = quad*4;
      float* gw = gatesL + wv*1056;
      #pragma unroll
      for (int r = 0; r < 4; ++r){
        gw[(col)*33      + rb + r]      = a00[r];
        gw[(16+col)*33   + rb + r]      = a01[r];
        gw[(col)*33      + 16 + rb + r] = a10[r];
        gw[(16+col)*33   + 16 + rb + r] = a11[r];
      }
    }
    __syncthreads();                               // B3: gates ready

    // ---- gate nonlinearity + state + hbuf ----
    {
      float fa = 0.f;
      #pragma unroll
      for (int p = 0; p < 4; ++p){
        int jl = jq*4 + p;
        float gi = gatesL[0*1056 + jl*33 + bb] + bia[p][0];
        float gf = gatesL[1*1056 + jl*33 + bb] + bia[p][1];
        float gg = gatesL[2*1056 + jl*33 + bb] + bia[p][2];
        float go = gatesL[3*1056 + jl*33 + bb] + bia[p][3];
        float iv = sigm(gi), fv = sigm(gf), gv = tanh_(gg), ov = sigm(go);
        float cc = fv*cst[jl*33 + bb] + iv*gv;
        cst[jl*33 + bb] = cc;
        float h = ov*tanh_(cc);
        unsigned short hh = f2bf(h);
        unsigned short hl = f2bf(h - bf2f(hh));
        hbuf[bb*72 + jl]      = hh;
        hbuf[bb*72 + 32 + jl] = hl;
        if (LAYER == 1) fa = fmaf(h, wfcv[p], fa);
      }
      if (LAYER == 1 && t == TT-1) fcp = fa;
    }
    __syncthreads();                               // B4: hbuf ready

    // ---- ring write: 4 agent-scope dword stores per thread, slice-contiguous ----
    {
      unsigned* rwdw = (unsigned*)((LAYER ? ring1 : ring0)
                       + ((size_t)((t&7)*256 + bg*32 + b8))*512) + sl*32 + sub*4;
      const unsigned* hb = (const unsigned*)hbuf + b8*36 + sub*4;
      #pragma unroll
      for (int i = 0; i < 4; ++i) st_ring(rwdw + i, hb[i]);
    }
    // order: this wave's ring stores reach the coherence point before the barrier;
    // tid0's flag store after the barrier is therefore globally ordered after them.
    asm volatile("s_waitcnt vmcnt(0)" ::: "memory");
    __syncthreads();                               // B5
    if (tid == 0) st_flag((LAYER ? f1line : f0line) + sl, t+1);
  }

  // ---- FC epilogue ----
  if (LAYER == 1){
    __syncthreads();
    float* red = gatesL;
    red[tid] = fcp;
    __syncthreads();
    if (tid < 32){
      float sm = 0.f;
      #pragma unroll
      for (int q = 0; q < 8; ++q) sm += red[q*32 + tid];
      if (sl == 0) sm += bfc[0];
      atomicAdd(&out[bg*32 + tid], sm);
    }
  }
}

__global__ __launch_bounds__(256,1) void lstm_pipe(const float* __restrict__ x, char* __restrict__ ws,
                                                   const float* __restrict__ Wfc, const float* __restrict__ bfc,
                                                   float* __restrict__ out){
  __shared__ unsigned short Apan[32*1032];   // 66,048 B
  __shared__ float gatesL[4224];             // 16,896 B [4 g][32 j][33]
  __shared__ float cst[1056];                //  4,224 B [32 j][33]
  __shared__ unsigned short hbuf[32*72];     //  4,608 B [32 b][hi32|lo32|pad8]
  const int bid = blockIdx.x;
  // bid = sl*16 + layer*8 + bg: all 16 blocks of a bg share bid%8 -> same XCD
  // under round-robin dispatch (perf heuristic only; correctness is placement-free).
  const int bg = bid & 7, layer = (bid >> 3) & 1, sl = bid >> 4;
  if (layer == 0) run_layer<0>(x, ws, Wfc, bfc, out, bg, sl, Apan, gatesL, cst, hbuf);
  else            run_layer<1>(x, ws, Wfc, bfc, out, bg, sl, Apan, gatesL, cst, hbuf);
}

extern "C" void kernel_launch(void* const* d_in, const int* in_sizes, int n_in,
                              void* d_out, int out_size, void* d_ws, size_t ws_size,
                              hipStream_t stream) {
  const float* x    = (const float*)d_in[0];
  const float* Wih0 = (const float*)d_in[1];
  const float* Whh0 = (const float*)d_in[2];
  const float* bih0 = (const float*)d_in[3];
  const float* bhh0 = (const float*)d_in[4];
  const float* Wih1 = (const float*)d_in[5];
  const float* Whh1 = (const float*)d_in[6];
  const float* bih1 = (const float*)d_in[7];
  const float* bhh1 = (const float*)d_in[8];
  const float* Wfc  = (const float*)d_in[9];
  const float* bfc  = (const float*)d_in[10];
  float* out = (float*)d_out;
  char* ws   = (char*)d_ws;
  (void)in_sizes; (void)n_in; (void)out_size; (void)ws_size;

  // total pack items: 589824+1048576+2048+131072+256+512 = 1,772,288 = 6923*256
  pack_all<<<6923, 256, 0, stream>>>(Wih0, Whh0, bih0, bhh0, Wih1, Whh1, bih1, bhh1, ws, out);
  lstm_pipe<<<128, 256, 0, stream>>>(x, ws, Wfc, bfc, out);
}

// Round 7
// 4903.456 us; speedup vs baseline: 6.9689x; 1.4311x over previous
//
#include <hip/hip_runtime.h>

// LSTMForecast: B=256, T=512, IN=32, H=256, OUT=1, fp32.
// Round 7: spill-free weights, fragment-layout rings, 1-word flags.
//   - 256 blocks: (layer, sl16 j-slice, bg). L1 weights = 32 frags = 128 VGPR (fits).
//   - Rings hold data in MFMA A-fragment layout -> staging is a linear 8B copy,
//     MFMA ds_read_b128 lane-consecutive (conflict-free).
//   - One flag word per (layer,bg): producers fetch_add(relaxed,agent); reader polls 1 dword.
//   - Numerics identical to R6 (split-bf16 4-product MFMA, absmax 0.0).

#define TT 512

typedef short v8s __attribute__((ext_vector_type(8)));
typedef float v4f __attribute__((ext_vector_type(4)));
typedef unsigned short u4h __attribute__((ext_vector_type(4)));

// ws byte offsets
constexpr size_t OFF_W0    = 0;          // [sl16][g4][kc9][spl2][lane64][e8] sh = 1,179,648 B
constexpr size_t OFF_W1    = 1179648;    // [sl16][g4][kc16][spl2][lane64][e8] = 2,097,152 B
constexpr size_t OFF_BC0   = 3276800;    // fp32[1024]
constexpr size_t OFF_BC1   = 3280896;    // fp32[1024]
constexpr size_t OFF_FLG   = 3284992;    // f0[bg] at bg*128; f1[bg] at 1024+bg*128
constexpr size_t OFF_RING0 = 3287040;    // [slot8][bg8][spl2][half2][c8][lane64][e8] sh = 2 MB
constexpr size_t OFF_RING1 = 5384192;    // same; end 7,481,344

__device__ __forceinline__ float bf2f(unsigned short h){ return __uint_as_float(((unsigned)h)<<16); }
__device__ __forceinline__ unsigned short f2bf(float f){
  unsigned u = __float_as_uint(f);
  u += 0x7FFF + ((u>>16)&1);
  return (unsigned short)(u>>16);
}
__device__ __forceinline__ float sigm(float v){ return 1.0f/(1.0f + expf(-v)); }
__device__ __forceinline__ float tanh_(float v){
  float a = fabsf(v);
  float e = expf(-2.0f*a);
  float r = (1.0f - e)/(1.0f + e);
  return copysignf(r, v);
}
__device__ __forceinline__ int ld_flag(const int* p){
  return __hip_atomic_load(p, __ATOMIC_RELAXED, __HIP_MEMORY_SCOPE_AGENT);
}
__device__ __forceinline__ void add_flag(int* p){
  (void)__hip_atomic_fetch_add(p, 1, __ATOMIC_RELAXED, __HIP_MEMORY_SCOPE_AGENT);
}
__device__ __forceinline__ unsigned long long ld_r64(const unsigned long long* p){
  return __hip_atomic_load(p, __ATOMIC_RELAXED, __HIP_MEMORY_SCOPE_AGENT);
}
__device__ __forceinline__ void st_r64(unsigned long long* p, unsigned long long v){
  __hip_atomic_store(p, v, __ATOMIC_RELAXED, __HIP_MEMORY_SCOPE_AGENT);
}

// ---------------- pack kernel ----------------
__global__ void pack_all(const float* __restrict__ Wih0, const float* __restrict__ Whh0,
                         const float* __restrict__ bih0, const float* __restrict__ bhh0,
                         const float* __restrict__ Wih1, const float* __restrict__ Whh1,
                         const float* __restrict__ bih1, const float* __restrict__ bhh1,
                         char* __restrict__ ws, float* __restrict__ out){
  int idx = blockIdx.x*256 + threadIdx.x;
  if (idx < 589824){    // W0: [sl][g][kc9][spl][lane][e]
    int e = idx&7, lane = (idx>>3)&63, spl = (idx>>9)&1, r = idx>>10;
    int kc = r%9, r2 = r/9;
    int g = r2&3, sl = r2>>2;
    int row = g*256 + sl*16 + (lane&15);
    int k = kc*32 + (lane>>4)*8 + e;
    float w = (k < 32) ? Wih0[row*32 + k] : Whh0[row*256 + (k-32)];
    unsigned short hi = f2bf(w);
    ((unsigned short*)(ws + OFF_W0))[idx] = spl ? f2bf(w - bf2f(hi)) : hi;
    return;
  }
  idx -= 589824;
  if (idx < 1048576){   // W1: [sl][g][kc16][spl][lane][e]
    int e = idx&7, lane = (idx>>3)&63, spl = (idx>>9)&1, r = idx>>10;
    int kc = r&15, r2 = r>>4;
    int g = r2&3, sl = r2>>2;
    int row = g*256 + sl*16 + (lane&15);
    int k = kc*32 + (lane>>4)*8 + e;
    float w = (k < 256) ? Wih1[row*256 + k] : Whh1[row*256 + (k-256)];
    unsigned short hi = f2bf(w);
    ((unsigned short*)(ws + OFF_W1))[idx] = spl ? f2bf(w - bf2f(hi)) : hi;
    return;
  }
  idx -= 1048576;
  if (idx < 2048){      // combined biases [g*256+j]
    float* bc = (float*)(ws + (idx < 1024 ? OFF_BC0 : OFF_BC1));
    int j = idx & 1023;
    bc[j] = (idx < 1024) ? (bih0[j]+bhh0[j]) : (bih1[j]+bhh1[j]);
    return;
  }
  idx -= 2048;
  if (idx < 131072){    // zero ring slot 7 (h[-1]) of both rings (65536 dwords each)
    int* rz = (int*)(ws + (idx < 65536 ? OFF_RING0 : OFF_RING1) + (size_t)7*262144);
    rz[idx & 65535] = 0;
    return;
  }
  idx -= 131072;
  if (idx < 256){ out[idx] = 0.f; return; }
  idx -= 256;
  if (idx < 512){ ((int*)(ws + OFF_FLG))[idx] = 0; return; }
}

// ---------------- persistent layer worker ----------------
template<int LAYER>
__device__ void run_layer(const float* __restrict__ x, char* __restrict__ ws,
                          const float* __restrict__ Wfc, const float* __restrict__ bfc,
                          float* __restrict__ out, int bg, int sl,
                          short* Afr, float* gatesL, float* cst, unsigned short* hbuf){
  constexpr int NKC  = LAYER ? 16 : 9;       // K chunks per split half
  constexpr int HSTR = NKC*512;              // half stride (shorts) in A panel
  constexpr int SSTR = 2*HSTR;               // spl stride
  constexpr int NFR  = 2*NKC;                // B frags per wave: [kc][spl]

  int* f0 = (int*)(ws + OFF_FLG + (size_t)bg*128);
  int* f1 = (int*)(ws + OFF_FLG + 1024 + (size_t)bg*128);
  unsigned long long* ring0 = (unsigned long long*)(ws + OFF_RING0);
  unsigned long long* ring1 = (unsigned long long*)(ws + OFF_RING1);

  const int tid  = threadIdx.x;
  const int lane = tid & 63;
  const int g    = tid >> 6;       // wave == gate (i,f,g,o)
  const int m    = lane & 15;      // j_loc in C; b-row in A-frag read
  const int quad = lane >> 4;

  // ---- persistent B-fragments: L1 = 32 frags = 128 VGPR (fits, no spill) ----
  const unsigned short* wp = (const unsigned short*)(ws + (LAYER ? OFF_W1 : OFF_W0))
                             + (size_t)(sl*4 + g)*NFR*512 + lane*8;
  v8s bfr[NFR];
  #pragma unroll
  for (int f = 0; f < NFR; ++f) bfr[f] = *(const v8s*)(wp + f*512);

  // ---- gate-phase constants: thread (bb, jp) owns (b=bb, j = sl*16 + jp*2 + p) ----
  const int bb = tid & 31, jp = tid >> 5;
  const float* bcp = (const float*)(ws + (LAYER ? OFF_BC1 : OFF_BC0));
  float bia[2][4];
  #pragma unroll
  for (int p = 0; p < 2; ++p)
    #pragma unroll
    for (int gg = 0; gg < 4; ++gg) bia[p][gg] = bcp[gg*256 + sl*16 + jp*2 + p];
  float wfcv[2] = {0.f, 0.f};
  if (LAYER == 1){ wfcv[0] = Wfc[sl*16 + jp*2]; wfcv[1] = Wfc[sl*16 + jp*2 + 1]; }
  float fcp = 0.f;

  // hbuf geometry for this thread's h writes
  const int half_b  = bb >> 4;
  const int laneloc = ((jp*2) >> 3)*16 + (bb & 15);
  const int e0h     = ((jp*2) & 7) >> 1;          // uint index within 8-short group

  // zero c-state [32][17]
  for (int i = tid; i < 544; i += 256) cst[i] = 0.f;
  __syncthreads();

  const int xb = tid >> 3, xs = tid & 7;          // x staging role (L0)
  int kn0 = 0, kn1 = 0;                            // cached flag values (tid0)

  for (int t = 0; t < TT; ++t){
    float4 xv;
    if (LAYER == 0)
      xv = *(const float4*)(x + ((size_t)(bg*32 + xb)*TT + t)*32 + xs*4);

    if (LAYER == 0){
      // ---- wait peers' h0[t-1] + back-pressure, then stage x + h0 ----
      if (tid == 0){
        int need0 = 16*t, need1 = 16*(t-7);
        if (kn0 < need0) while ((kn0 = ld_flag(f0)) < need0) __builtin_amdgcn_s_sleep(1);
        if (need1 > 0 && kn1 < need1) while ((kn1 = ld_flag(f1)) < need1) __builtin_amdgcn_s_sleep(1);
      }
      __syncthreads();
      // x chunk (c=0) fragment writes
      {
        u4h hi4, lo4;
        hi4.x = f2bf(xv.x); lo4.x = f2bf(xv.x - bf2f(hi4.x));
        hi4.y = f2bf(xv.y); lo4.y = f2bf(xv.y - bf2f(hi4.y));
        hi4.z = f2bf(xv.z); lo4.z = f2bf(xv.z - bf2f(hi4.z));
        hi4.w = f2bf(xv.w); lo4.w = f2bf(xv.w - bf2f(hi4.w));
        int lx = (xs>>1)*16 + (xb&15), hx = xb>>4, ex = (xs&1)*4;
        *(u4h*)(Afr + 0*SSTR + hx*HSTR + lx*8 + ex) = hi4;
        *(u4h*)(Afr + 1*SSTR + hx*HSTR + lx*8 + ex) = lo4;
      }
      // h0[t-1]: linear 32KB ring read -> frag panel at chunk c+1
      {
        const unsigned long long* src = ring0 + (size_t)(((t+7)&7))*32768 + (size_t)bg*4096;
        #pragma unroll
        for (int i = 0; i < 16; ++i){
          int u = i*256 + tid;
          unsigned long long v = ld_r64(src + u);
          int spl = u>>11, hf = (u>>10)&1, c = (u>>7)&7, rest = u&127;
          *(unsigned long long*)(Afr + spl*SSTR + hf*HSTR + (c+1)*512 + rest*4) = v;
        }
      }
      __syncthreads();
    } else {
      // ---- stage h1[t-1] early (own-layer flag), then wait h0[t] ----
      if (tid == 0){
        int need1 = 16*t;
        if (need1 > 0 && kn1 < need1) while ((kn1 = ld_flag(f1)) < need1) __builtin_amdgcn_s_sleep(1);
      }
      __syncthreads();
      {
        const unsigned long long* src = ring1 + (size_t)(((t+7)&7))*32768 + (size_t)bg*4096;
        #pragma unroll
        for (int i = 0; i < 16; ++i){
          int u = i*256 + tid;
          unsigned long long v = ld_r64(src + u);
          int spl = u>>11, hf = (u>>10)&1, c = (u>>7)&7, rest = u&127;
          *(unsigned long long*)(Afr + spl*SSTR + hf*HSTR + (c+8)*512 + rest*4) = v;
        }
      }
      if (tid == 0){
        int need0 = 16*(t+1);
        if (kn0 < need0) while ((kn0 = ld_flag(f0)) < need0) __builtin_amdgcn_s_sleep(1);
      }
      __syncthreads();
      {
        const unsigned long long* src = ring0 + (size_t)((t&7))*32768 + (size_t)bg*4096;
        #pragma unroll
        for (int i = 0; i < 16; ++i){
          int u = i*256 + tid;
          unsigned long long v = ld_r64(src + u);
          int spl = u>>11, hf = (u>>10)&1, c = (u>>7)&7, rest = u&127;
          *(unsigned long long*)(Afr + spl*SSTR + hf*HSTR + c*512 + rest*4) = v;
        }
      }
      __syncthreads();
    }

    // ---- MFMA: 4-product split; wave g computes gates[g] for 32b x 16j ----
    v4f acc0 = {0,0,0,0}, acc1 = {0,0,0,0};
    #pragma unroll
    for (int sa = 0; sa < 2; ++sa){
      #pragma unroll
      for (int c = 0; c < NKC; ++c){
        v8s A0 = *(const v8s*)(Afr + sa*SSTR + 0*HSTR + c*512 + lane*8);
        v8s A1 = *(const v8s*)(Afr + sa*SSTR + 1*HSTR + c*512 + lane*8);
        v8s Bh = bfr[c*2+0], Bl = bfr[c*2+1];
        acc0 = __builtin_amdgcn_mfma_f32_16x16x32_bf16(A0, Bh, acc0, 0,0,0);
        acc0 = __builtin_amdgcn_mfma_f32_16x16x32_bf16(A0, Bl, acc0, 0,0,0);
        acc1 = __builtin_amdgcn_mfma_f32_16x16x32_bf16(A1, Bh, acc1, 0,0,0);
        acc1 = __builtin_amdgcn_mfma_f32_16x16x32_bf16(A1, Bl, acc1, 0,0,0);
      }
    }
    // C layout: col = lane&15 = j_loc, row = quad*4+r = b(within half)
    {
      float* gw = gatesL + g*544;
      #pragma unroll
      for (int r = 0; r < 4; ++r){
        gw[(quad*4 + r)*17 + m]      = acc0[r];
        gw[(16 + quad*4 + r)*17 + m] = acc1[r];
      }
    }
    __syncthreads();

    // ---- gate nonlinearity + state + hbuf (frag-layout) ----
    {
      float hv[2];
      #pragma unroll
      for (int p = 0; p < 2; ++p){
        int jl = jp*2 + p;
        float gi = gatesL[0*544 + bb*17 + jl] + bia[p][0];
        float gf = gatesL[1*544 + bb*17 + jl] + bia[p][1];
        float gG = gatesL[2*544 + bb*17 + jl] + bia[p][2];
        float go = gatesL[3*544 + bb*17 + jl] + bia[p][3];
        float iv = sigm(gi), fv = sigm(gf), gv = tanh_(gG), ov = sigm(go);
        float cc = fv*cst[bb*17 + jl] + iv*gv;
        cst[bb*17 + jl] = cc;
        hv[p] = ov*tanh_(cc);
      }
      unsigned short h0h = f2bf(hv[0]), h1h = f2bf(hv[1]);
      unsigned short h0l = f2bf(hv[0] - bf2f(h0h)), h1l = f2bf(hv[1] - bf2f(h1h));
      unsigned* hb = (unsigned*)hbuf;
      hb[          half_b*128 + laneloc*4 + e0h] = (unsigned)h0h | ((unsigned)h1h << 16);
      hb[256 +     half_b*128 + laneloc*4 + e0h] = (unsigned)h0l | ((unsigned)h1l << 16);
      if (LAYER == 1 && t == TT-1) fcp = hv[0]*wfcv[0] + hv[1]*wfcv[1];
    }
    __syncthreads();

    // ---- ring write: one contiguous 8B agent store per thread ----
    {
      unsigned long long v = ((const unsigned long long*)hbuf)[tid];
      size_t dst = (size_t)((t&7))*32768 + (size_t)bg*4096
                 + (size_t)(tid>>7)*2048 + (size_t)((tid>>6)&1)*1024
                 + (size_t)(sl>>1)*128 + (size_t)(sl&1)*64 + (tid&63);
      st_r64((LAYER ? ring1 : ring0) + dst, v);
    }
    asm volatile("s_waitcnt vmcnt(0)" ::: "memory");
    __syncthreads();
    if (tid == 0) add_flag(LAYER ? f1 : f0);
  }

  // ---- FC epilogue ----
  if (LAYER == 1){
    __syncthreads();
    gatesL[tid] = fcp;
    __syncthreads();
    if (tid < 32){
      float sm = 0.f;
      #pragma unroll
      for (int q = 0; q < 8; ++q) sm += gatesL[q*32 + tid];
      if (sl == 0) sm += bfc[0];
      atomicAdd(&out[bg*32 + tid], sm);
    }
  }
}

__global__ __launch_bounds__(256,1) void lstm_pipe(const float* __restrict__ x, char* __restrict__ ws,
                                                   const float* __restrict__ Wfc, const float* __restrict__ bfc,
                                                   float* __restrict__ out){
  __shared__ __align__(16) short Afr[32768];          // 65,536 B (L1 panel; L0 uses 36,864)
  __shared__ __align__(16) float gatesL[2176];        //  8,704 B [4 g][32 b][17]
  __shared__ __align__(16) float cst[544];            //  2,176 B [32 b][17]
  __shared__ __align__(16) unsigned short hbuf[1024]; //  2,048 B [spl2][half2][lane32][e8]
  const int bid = blockIdx.x;
  // bid = (layer*16 + sl)*8 + bg : bid%8 = bg -> bg-cluster per XCD round-robin (perf only)
  const int bg = bid & 7, r = bid >> 3, layer = r >> 4, sl = r & 15;
  if (layer == 0) run_layer<0>(x, ws, Wfc, bfc, out, bg, sl, Afr, gatesL, cst, hbuf);
  else            run_layer<1>(x, ws, Wfc, bfc, out, bg, sl, Afr, gatesL, cst, hbuf);
}

extern "C" void kernel_launch(void* const* d_in, const int* in_sizes, int n_in,
                              void* d_out, int out_size, void* d_ws, size_t ws_size,
                              hipStream_t stream) {
  const float* x    = (const float*)d_in[0];
  const float* Wih0 = (const float*)d_in[1];
  const float* Whh0 = (const float*)d_in[2];
  const float* bih0 = (const float*)d_in[3];
  const float* bhh0 = (const float*)d_in[4];
  const float* Wih1 = (const float*)d_in[5];
  const float* Whh1 = (const float*)d_in[6];
  const float* bih1 = (const float*)d_in[7];
  const float* bhh1 = (const float*)d_in[8];
  const float* Wfc  = (const float*)d_in[9];
  const float* bfc  = (const float*)d_in[10];
  float* out = (float*)d_out;
  char* ws   = (char*)d_ws;
  (void)in_sizes; (void)n_in; (void)out_size; (void)ws_size;

  // pack items: 589824+1048576+2048+131072+256+512 = 1,772,288 = 6923*256
  pack_all<<<6923, 256, 0, stream>>>(Wih0, Whh0, bih0, bhh0, Wih1, Whh1, bih1, bhh1, ws, out);
  lstm_pipe<<<256, 256, 0, stream>>>(x, ws, Wfc, bfc, out);
}

// Round 8
// 3838.507 us; speedup vs baseline: 8.9024x; 1.2774x over previous
//
#include <hip/hip_runtime.h>

// LSTMForecast: B=256, T=512, IN=32, H=256, OUT=1, fp32.
// Round 8: VGPR-pinned weights, per-wave seq sync, 3-product split.
//   - 256 blocks: (layer, sl16 j-slice, bg8). Weights bf16 hi+lo as MFMA B-frags,
//     pinned in VGPRs via asm anti-remat barrier (R7: compiler rematerialized).
//   - Sync: per-(producer,wave) seq words, release-stored after per-wave vmcnt(0)
//     (no RMW, no end-of-step barrier). Consumers poll per-wave (4 producers each),
//     stage as ready. Back-pressure: wave0 polls consumer line (depth-8 ring).
//   - 3-product split MFMA (hh + hl + lh; ll dropped: err ~1e-6 << 8.5e-4 thr).

#define TT 512

typedef short v8s __attribute__((ext_vector_type(8)));
typedef float v4f __attribute__((ext_vector_type(4)));
typedef unsigned short u4h __attribute__((ext_vector_type(4)));

// ws byte offsets
constexpr size_t OFF_W0    = 0;          // [sl16][g4][kc9][spl2][lane64][e8] sh = 1,179,648 B
constexpr size_t OFF_W1    = 1179648;    // [sl16][g4][kc16][spl2][lane64][e8] = 2,097,152 B
constexpr size_t OFF_BC0   = 3276800;    // fp32[1024]
constexpr size_t OFF_BC1   = 3280896;    // fp32[1024]
constexpr size_t OFF_SEQ   = 3284992;    // int [layer2][bg8][producer16][wave4] = 4096 B
constexpr size_t OFF_RING0 = 3289088;    // [slot8][bg8][4096 u64] = 2 MB
constexpr size_t OFF_RING1 = 5386240;    // same; end 7,483,392

__device__ __forceinline__ float bf2f(unsigned short h){ return __uint_as_float(((unsigned)h)<<16); }
__device__ __forceinline__ unsigned short f2bf(float f){
  unsigned u = __float_as_uint(f);
  u += 0x7FFF + ((u>>16)&1);
  return (unsigned short)(u>>16);
}
__device__ __forceinline__ float sigm(float v){ return 1.0f/(1.0f + expf(-v)); }
__device__ __forceinline__ float tanh_(float v){
  float a = fabsf(v);
  float e = expf(-2.0f*a);
  float r = (1.0f - e)/(1.0f + e);
  return copysignf(r, v);
}
__device__ __forceinline__ int ld_flag(const int* p){
  return __hip_atomic_load(p, __ATOMIC_RELAXED, __HIP_MEMORY_SCOPE_AGENT);
}
__device__ __forceinline__ void st_flag(int* p, int v){
  __hip_atomic_store(p, v, __ATOMIC_RELAXED, __HIP_MEMORY_SCOPE_AGENT);
}
__device__ __forceinline__ unsigned long long ld_r64(const unsigned long long* p){
  return __hip_atomic_load(p, __ATOMIC_RELAXED, __HIP_MEMORY_SCOPE_AGENT);
}
__device__ __forceinline__ void st_r64(unsigned long long* p, unsigned long long v){
  __hip_atomic_store(p, v, __ATOMIC_RELAXED, __HIP_MEMORY_SCOPE_AGENT);
}
__device__ __forceinline__ int wave_min16(int v){
  v = min(v, __shfl_xor(v, 1, 64));
  v = min(v, __shfl_xor(v, 2, 64));
  v = min(v, __shfl_xor(v, 4, 64));
  v = min(v, __shfl_xor(v, 8, 64));
  return v;
}
// poll 16 contiguous seq words (producers 4w..4w+3 x 4 sub-waves); uniform result
__device__ __forceinline__ int poll_line16(const int* base, int lane, int need, int kn){
  if (kn >= need) return kn;
  for(;;){
    int v = ld_flag(base + (lane & 15));
    v = wave_min16(v);
    if (v >= need) return v;
    __builtin_amdgcn_s_sleep(1);
  }
}
// poll all 64 words of a (layer,bg) line
__device__ __forceinline__ int poll_line64(const int* base, int lane, int need, int kn){
  if (kn >= need) return kn;
  for(;;){
    int v = ld_flag(base + lane);
    v = wave_min16(v);
    v = min(v, __shfl_xor(v, 16, 64));
    v = min(v, __shfl_xor(v, 32, 64));
    if (v >= need) return v;
    __builtin_amdgcn_s_sleep(1);
  }
}

// stage 4 producers' slices (2 KB each) for this wave: 16 independent 8B loads -> LDS
template<int SSTR, int HSTR>
__device__ __forceinline__ void stage4(const unsigned long long* ring, size_t slotbase,
                                       int w, int lane, short* Afr, int cadd){
  unsigned long long v[4][4];
  #pragma unroll
  for (int q = 0; q < 4; ++q){
    int p = w*4 + q;
    const unsigned long long* b = ring + slotbase + (size_t)((p>>1)*128 + (p&1)*64);
    #pragma unroll
    for (int sh = 0; sh < 4; ++sh)
      v[q][sh] = ld_r64(b + (sh>>1)*2048 + (sh&1)*1024 + lane);
  }
  #pragma unroll
  for (int q = 0; q < 4; ++q){
    int p = w*4 + q;
    #pragma unroll
    for (int sh = 0; sh < 4; ++sh){
      int spl = sh>>1, hf = sh&1;
      *(unsigned long long*)(Afr + spl*SSTR + hf*HSTR
                             + ((p>>1)+cadd)*512 + ((p&1)*64+lane)*4) = v[q][sh];
    }
  }
}

// ---------------- pack kernel ----------------
__global__ void pack_all(const float* __restrict__ Wih0, const float* __restrict__ Whh0,
                         const float* __restrict__ bih0, const float* __restrict__ bhh0,
                         const float* __restrict__ Wih1, const float* __restrict__ Whh1,
                         const float* __restrict__ bih1, const float* __restrict__ bhh1,
                         char* __restrict__ ws, float* __restrict__ out){
  int idx = blockIdx.x*256 + threadIdx.x;
  if (idx < 589824){    // W0: [sl][g][kc9][spl][lane][e]
    int e = idx&7, lane = (idx>>3)&63, spl = (idx>>9)&1, r = idx>>10;
    int kc = r%9, r2 = r/9;
    int g = r2&3, sl = r2>>2;
    int row = g*256 + sl*16 + (lane&15);
    int k = kc*32 + (lane>>4)*8 + e;
    float w = (k < 32) ? Wih0[row*32 + k] : Whh0[row*256 + (k-32)];
    unsigned short hi = f2bf(w);
    ((unsigned short*)(ws + OFF_W0))[idx] = spl ? f2bf(w - bf2f(hi)) : hi;
    return;
  }
  idx -= 589824;
  if (idx < 1048576){   // W1: [sl][g][kc16][spl][lane][e]
    int e = idx&7, lane = (idx>>3)&63, spl = (idx>>9)&1, r = idx>>10;
    int kc = r&15, r2 = r>>4;
    int g = r2&3, sl = r2>>2;
    int row = g*256 + sl*16 + (lane&15);
    int k = kc*32 + (lane>>4)*8 + e;
    float w = (k < 256) ? Wih1[row*256 + k] : Whh1[row*256 + (k-256)];
    unsigned short hi = f2bf(w);
    ((unsigned short*)(ws + OFF_W1))[idx] = spl ? f2bf(w - bf2f(hi)) : hi;
    return;
  }
  idx -= 1048576;
  if (idx < 2048){      // combined biases [g*256+j]
    float* bc = (float*)(ws + (idx < 1024 ? OFF_BC0 : OFF_BC1));
    int j = idx & 1023;
    bc[j] = (idx < 1024) ? (bih0[j]+bhh0[j]) : (bih1[j]+bhh1[j]);
    return;
  }
  idx -= 2048;
  if (idx < 131072){    // zero ring slot 7 (h[-1]) of both rings (65536 dwords each)
    int* rz = (int*)(ws + (idx < 65536 ? OFF_RING0 : OFF_RING1) + (size_t)7*262144);
    rz[idx & 65535] = 0;
    return;
  }
  idx -= 131072;
  if (idx < 256){ out[idx] = 0.f; return; }
  idx -= 256;
  if (idx < 1024){ ((int*)(ws + OFF_SEQ))[idx] = 0; return; }
}

// ---------------- persistent layer worker ----------------
template<int LAYER>
__device__ void run_layer(const float* __restrict__ x, char* __restrict__ ws,
                          const float* __restrict__ Wfc, const float* __restrict__ bfc,
                          float* __restrict__ out, int bg, int sl,
                          short* Afr, float* gatesL, float* cst, unsigned short* hbuf){
  constexpr int NKC  = LAYER ? 16 : 9;       // K chunks per split half
  constexpr int HSTR = NKC*512;              // half stride (shorts) in A panel
  constexpr int SSTR = 2*HSTR;               // spl stride
  constexpr int NFR  = 2*NKC;                // B frags per wave: [kc][spl]

  int* seq0 = (int*)(ws + OFF_SEQ) + bg*64;          // layer0 line (64 words)
  int* seq1 = (int*)(ws + OFF_SEQ) + (8+bg)*64;      // layer1 line
  unsigned long long* ring0 = (unsigned long long*)(ws + OFF_RING0);
  unsigned long long* ring1 = (unsigned long long*)(ws + OFF_RING1);

  const int tid  = threadIdx.x;
  const int lane = tid & 63;
  const int wv   = tid >> 6;       // wave == gate (i,f,g,o)
  const int m    = lane & 15;
  const int quad = lane >> 4;

  // ---- persistent B-fragments, pinned (anti-remat asm) ----
  const unsigned short* wp = (const unsigned short*)(ws + (LAYER ? OFF_W1 : OFF_W0))
                             + (size_t)(sl*4 + wv)*NFR*512 + lane*8;
  v8s bfr[NFR];
  #pragma unroll
  for (int f = 0; f < NFR; ++f){
    v8s tmp = *(const v8s*)(wp + f*512);
    asm volatile("" : "+v"(tmp));            // opaque: cannot rematerialize by reloading
    bfr[f] = tmp;
  }

  // ---- gate-phase constants: thread (bb, jp) owns (b=bb, j = sl*16 + jp*2 + p) ----
  const int bb = tid & 31, jp = tid >> 5;
  const float* bcp = (const float*)(ws + (LAYER ? OFF_BC1 : OFF_BC0));
  float bia[2][4];
  #pragma unroll
  for (int p = 0; p < 2; ++p)
    #pragma unroll
    for (int gg = 0; gg < 4; ++gg) bia[p][gg] = bcp[gg*256 + sl*16 + jp*2 + p];
  float wfcv[2] = {0.f, 0.f};
  if (LAYER == 1){ wfcv[0] = Wfc[sl*16 + jp*2]; wfcv[1] = Wfc[sl*16 + jp*2 + 1]; }
  float fcp = 0.f;

  // hbuf geometry for this thread's h writes
  const int half_b  = bb >> 4;
  const int laneloc = ((jp*2) >> 3)*16 + (bb & 15);
  const int e0h     = ((jp*2) & 7) >> 1;

  for (int i = tid; i < 544; i += 256) cst[i] = 0.f;
  __syncthreads();

  const int xb = tid >> 3, xs = tid & 7;     // x staging role (L0)
  int kn_a = 0, kn_b = 0;                    // cached line minima (per wave, uniform)

  for (int t = 0; t < TT; ++t){
    size_t slot_prev = (size_t)((t+7)&7)*32768 + (size_t)bg*4096;
    size_t slot_cur  = (size_t)(t&7)*32768 + (size_t)bg*4096;

    if (LAYER == 0){
      float4 xv = *(const float4*)(x + ((size_t)(bg*32 + xb)*TT + t)*32 + xs*4);
      // wait my 4 producers' h0[t-1], stage
      kn_a = poll_line16(seq0 + 16*wv, lane, t, kn_a);
      stage4<SSTR,HSTR>(ring0, slot_prev, wv, lane, Afr, 1);
      // x chunk (c=0) fragment writes
      {
        u4h hi4, lo4;
        hi4.x = f2bf(xv.x); lo4.x = f2bf(xv.x - bf2f(hi4.x));
        hi4.y = f2bf(xv.y); lo4.y = f2bf(xv.y - bf2f(hi4.y));
        hi4.z = f2bf(xv.z); lo4.z = f2bf(xv.z - bf2f(hi4.z));
        hi4.w = f2bf(xv.w); lo4.w = f2bf(xv.w - bf2f(hi4.w));
        int lx = (xs>>1)*16 + (xb&15), hx = xb>>4, ex = (xs&1)*4;
        *(u4h*)(Afr + 0*SSTR + hx*HSTR + lx*8 + ex) = hi4;
        *(u4h*)(Afr + 1*SSTR + hx*HSTR + lx*8 + ex) = lo4;
      }
      // back-pressure: L1 must have consumed slot being overwritten (depth 8)
      if (wv == 0 && t >= 8) kn_b = poll_line64(seq1, lane, t-7, kn_b);
    } else {
      // stage h1[t-1] (own-layer peers), then h0[t]
      kn_b = poll_line16(seq1 + 16*wv, lane, t, kn_b);
      stage4<SSTR,HSTR>(ring1, slot_prev, wv, lane, Afr, 8);
      kn_a = poll_line16(seq0 + 16*wv, lane, t+1, kn_a);
      stage4<SSTR,HSTR>(ring0, slot_cur, wv, lane, Afr, 0);
    }
    __syncthreads();                           // B1: Afr complete

    // ---- MFMA: 3-product split (hh, hl, lh) ----
    v4f acc0 = {0,0,0,0}, acc1 = {0,0,0,0};
    #pragma unroll
    for (int c = 0; c < NKC; ++c){
      v8s A0h = *(const v8s*)(Afr + 0*SSTR + 0*HSTR + c*512 + lane*8);
      v8s A1h = *(const v8s*)(Afr + 0*SSTR + 1*HSTR + c*512 + lane*8);
      v8s A0l = *(const v8s*)(Afr + 1*SSTR + 0*HSTR + c*512 + lane*8);
      v8s A1l = *(const v8s*)(Afr + 1*SSTR + 1*HSTR + c*512 + lane*8);
      v8s Bh = bfr[c*2+0], Bl = bfr[c*2+1];
      acc0 = __builtin_amdgcn_mfma_f32_16x16x32_bf16(A0h, Bh, acc0, 0,0,0);
      acc0 = __builtin_amdgcn_mfma_f32_16x16x32_bf16(A0h, Bl, acc0, 0,0,0);
      acc0 = __builtin_amdgcn_mfma_f32_16x16x32_bf16(A0l, Bh, acc0, 0,0,0);
      acc1 = __builtin_amdgcn_mfma_f32_16x16x32_bf16(A1h, Bh, acc1, 0,0,0);
      acc1 = __builtin_amdgcn_mfma_f32_16x16x32_bf16(A1h, Bl, acc1, 0,0,0);
      acc1 = __builtin_amdgcn_mfma_f32_16x16x32_bf16(A1l, Bh, acc1, 0,0,0);
    }
    // C layout: col = lane&15 = j_loc, row = quad*4+r = b(within half)
    {
      float* gw = gatesL + wv*544;
      #pragma unroll
      for (int r = 0; r < 4; ++r){
        gw[(quad*4 + r)*17 + m]      = acc0[r];
        gw[(16 + quad*4 + r)*17 + m] = acc1[r];
      }
    }
    __syncthreads();                           // B2: gates ready

    // ---- gate nonlinearity + state + hbuf ----
    {
      float hv[2];
      #pragma unroll
      for (int p = 0; p < 2; ++p){
        int jl = jp*2 + p;
        float gi = gatesL[0*544 + bb*17 + jl] + bia[p][0];
        float gf = gatesL[1*544 + bb*17 + jl] + bia[p][1];
        float gG = gatesL[2*544 + bb*17 + jl] + bia[p][2];
        float go = gatesL[3*544 + bb*17 + jl] + bia[p][3];
        float iv = sigm(gi), fv = sigm(gf), gv = tanh_(gG), ov = sigm(go);
        float cc = fv*cst[bb*17 + jl] + iv*gv;
        cst[bb*17 + jl] = cc;
        hv[p] = ov*tanh_(cc);
      }
      unsigned short h0h = f2bf(hv[0]), h1h = f2bf(hv[1]);
      unsigned short h0l = f2bf(hv[0] - bf2f(h0h)), h1l = f2bf(hv[1] - bf2f(h1h));
      unsigned* hb = (unsigned*)hbuf;
      hb[      half_b*128 + laneloc*4 + e0h] = (unsigned)h0h | ((unsigned)h1h << 16);
      hb[256 + half_b*128 + laneloc*4 + e0h] = (unsigned)h0l | ((unsigned)h1l << 16);
      if (LAYER == 1 && t == TT-1) fcp = hv[0]*wfcv[0] + hv[1]*wfcv[1];
    }
    __syncthreads();                           // B3: hbuf ready

    // ---- ring write (1x 8B/thread) + per-wave release ----
    {
      unsigned long long v = ((const unsigned long long*)hbuf)[tid];
      size_t dst = slot_cur + (size_t)(tid>>7)*2048 + (size_t)((tid>>6)&1)*1024
                 + (size_t)(sl>>1)*128 + (size_t)(sl&1)*64 + (tid&63);
      st_r64((LAYER ? ring1 : ring0) + dst, v);
    }
    asm volatile("s_waitcnt vmcnt(0)" ::: "memory");   // this wave's stores visible
    if (lane == 0) st_flag((LAYER ? seq1 : seq0) + sl*4 + wv, t+1);
    // no end-of-step barrier: next hbuf write is 2 barriers away (safe)
  }

  // ---- FC epilogue ----
  if (LAYER == 1){
    __syncthreads();
    gatesL[tid] = fcp;
    __syncthreads();
    if (tid < 32){
      float sm = 0.f;
      #pragma unroll
      for (int q = 0; q < 8; ++q) sm += gatesL[q*32 + tid];
      if (sl == 0) sm += bfc[0];
      atomicAdd(&out[bg*32 + tid], sm);
    }
  }
}

__global__ __launch_bounds__(256,1) void lstm_pipe(const float* __restrict__ x, char* __restrict__ ws,
                                                   const float* __restrict__ Wfc, const float* __restrict__ bfc,
                                                   float* __restrict__ out){
  __shared__ __align__(16) short Afr[32768];          // 65,536 B (L1 panel; L0 uses 36,864)
  __shared__ __align__(16) float gatesL[2176];        //  8,704 B [4 g][32 b][17]
  __shared__ __align__(16) float cst[544];            //  2,176 B [32 b][17]
  __shared__ __align__(16) unsigned short hbuf[1024]; //  2,048 B [spl2][half2][lane32][e8]
  const int bid = blockIdx.x;
  // bid = (layer*16 + sl)*8 + bg : bid%8 = bg -> bg-cluster per XCD round-robin (perf only)
  const int bg = bid & 7, r = bid >> 3, layer = r >> 4, sl = r & 15;
  if (layer == 0) run_layer<0>(x, ws, Wfc, bfc, out, bg, sl, Afr, gatesL, cst, hbuf);
  else            run_layer<1>(x, ws, Wfc, bfc, out, bg, sl, Afr, gatesL, cst, hbuf);
}

extern "C" void kernel_launch(void* const* d_in, const int* in_sizes, int n_in,
                              void* d_out, int out_size, void* d_ws, size_t ws_size,
                              hipStream_t stream) {
  const float* x    = (const float*)d_in[0];
  const float* Wih0 = (const float*)d_in[1];
  const float* Whh0 = (const float*)d_in[2];
  const float* bih0 = (const float*)d_in[3];
  const float* bhh0 = (const float*)d_in[4];
  const float* Wih1 = (const float*)d_in[5];
  const float* Whh1 = (const float*)d_in[6];
  const float* bih1 = (const float*)d_in[7];
  const float* bhh1 = (const float*)d_in[8];
  const float* Wfc  = (const float*)d_in[9];
  const float* bfc  = (const float*)d_in[10];
  float* out = (float*)d_out;
  char* ws   = (char*)d_ws;
  (void)in_sizes; (void)n_in; (void)out_size; (void)ws_size;

  // pack items: 589824+1048576+2048+131072+256+1024 = 1,772,800 = 6925*256
  pack_all<<<6925, 256, 0, stream>>>(Wih0, Whh0, bih0, bhh0, Wih1, Whh1, bih1, bhh1, ws, out);
  lstm_pipe<<<256, 256, 0, stream>>>(x, ws, Wfc, bfc, out);
}